// Round 1
// baseline (2808.202 us; speedup 1.0000x reference)
//
#include <hip/hip_runtime.h>

constexpr int K1 = 4096;   // input features per window-group (32*128)
constexpr int N1 = 512;    // hidden
constexpr int TT = 64;     // time steps after windowing
constexpr int NC = 40;     // classes (pre-pool)

// ---------------------------------------------------------------------------
// Kernel 1: h1 = x @ W1 + b1 (fp64 accumulate), then LIF1 over t in-block,
// writing spikes (0/1 as float) to S. Grid (256 batches, 512/64 col-blocks).
// BM=64 rows == exactly one batch's 64 timesteps, enabling the LIF fusion.
// ---------------------------------------------------------------------------
__global__ __launch_bounds__(256) void gemm1_lif1(const float* __restrict__ A,
                                                  const float* __restrict__ W1,
                                                  const float* __restrict__ b1,
                                                  float* __restrict__ S) {
  __shared__ double As[32][64];   // [k][m] 16 KB
  __shared__ double Bs[32][64];   // [k][n] 16 KB
  __shared__ double dS[64][64];   // [t][n] 32 KB accumulator tile

  const int tid = threadIdx.x;
  const int tx = tid & 15;        // n quad
  const int ty = tid >> 4;        // m quad
  const int b  = blockIdx.x;
  const int bn = blockIdx.y * 64;
  const int bm = b * 64;

  // global->LDS load mappings
  const int arow = tid >> 2;          // 0..63
  const int akq  = (tid & 3) * 8;     // 0,8,16,24
  const int bkr  = tid >> 3;          // 0..31
  const int bnq  = (tid & 7) * 8;     // 0..56

  const float* Aptr = A + (size_t)(bm + arow) * K1 + akq;
  const float* Bptr = W1 + (size_t)bkr * N1 + bn + bnq;

  double acc[4][4] = {};

  for (int k0 = 0; k0 < K1; k0 += 32) {
    const float4 a0 = *(const float4*)(Aptr + k0);
    const float4 a1 = *(const float4*)(Aptr + k0 + 4);
    const float4 w0 = *(const float4*)(Bptr + (size_t)k0 * N1);
    const float4 w1 = *(const float4*)(Bptr + (size_t)k0 * N1 + 4);
    __syncthreads();
    As[akq + 0][arow] = (double)a0.x;
    As[akq + 1][arow] = (double)a0.y;
    As[akq + 2][arow] = (double)a0.z;
    As[akq + 3][arow] = (double)a0.w;
    As[akq + 4][arow] = (double)a1.x;
    As[akq + 5][arow] = (double)a1.y;
    As[akq + 6][arow] = (double)a1.z;
    As[akq + 7][arow] = (double)a1.w;
    Bs[bkr][bnq + 0] = (double)w0.x;
    Bs[bkr][bnq + 1] = (double)w0.y;
    Bs[bkr][bnq + 2] = (double)w0.z;
    Bs[bkr][bnq + 3] = (double)w0.w;
    Bs[bkr][bnq + 4] = (double)w1.x;
    Bs[bkr][bnq + 5] = (double)w1.y;
    Bs[bkr][bnq + 6] = (double)w1.z;
    Bs[bkr][bnq + 7] = (double)w1.w;
    __syncthreads();
#pragma unroll
    for (int kk = 0; kk < 32; ++kk) {
      double a[4], w[4];
#pragma unroll
      for (int i = 0; i < 4; ++i) a[i] = As[kk][ty * 4 + i];
#pragma unroll
      for (int j = 0; j < 4; ++j) w[j] = Bs[kk][tx * 4 + j];
#pragma unroll
      for (int i = 0; i < 4; ++i)
#pragma unroll
        for (int j = 0; j < 4; ++j)
          acc[i][j] += a[i] * w[j];
    }
  }

  __syncthreads();
#pragma unroll
  for (int i = 0; i < 4; ++i)
#pragma unroll
    for (int j = 0; j < 4; ++j)
      dS[ty * 4 + i][tx * 4 + j] = acc[i][j];
  __syncthreads();

  // LIF1: one thread per output column, sequential over t (fp64 state)
  if (tid < 64) {
    const int col = tid;
    const double bias = (double)b1[bn + col];
    double mem = 0.0, spk = 0.0;
    for (int t = 0; t < TT; ++t) {
      const double y = dS[t][col] + bias;
      mem = mem * 0.5 * (1.0 - spk) + y;
      spk = (mem > 1.0) ? 1.0 : 0.0;
      S[((size_t)(b * TT + t)) * N1 + bn + col] = (float)spk;
    }
  }
}

// ---------------------------------------------------------------------------
// Kernel 2: per batch b: y[t,c] = S[b,t,:] @ W2[:,c] + b2[c] (fp64), LIF2
// over t carried in registers of lanes c<40, spike-count pooling -> out[b,0..3].
// Block = 320 threads = 8 h-chunks x 40 classes.
// ---------------------------------------------------------------------------
__global__ __launch_bounds__(320) void head_kernel(const float* __restrict__ S,
                                                   const float* __restrict__ W2,
                                                   const float* __restrict__ b2,
                                                   float* __restrict__ out) {
  __shared__ float w2s[N1 * NC];   // 80 KB, [h][c]
  __shared__ float srow[N1];
  __shared__ double part[320];
  __shared__ double red[NC];

  const int tid = threadIdx.x;
  const int b = blockIdx.x;

  for (int i = tid; i < N1 * NC; i += 320) w2s[i] = W2[i];

  const int q  = tid / NC;    // 0..7  -> h chunk
  const int c  = tid % NC;    // class
  const int h0 = q * 64;

  double mem = 0.0, spk = 0.0, ssum = 0.0;
  const double bias = (double)b2[c];

  for (int t = 0; t < TT; ++t) {
    const float* sp = S + ((size_t)(b * TT + t)) * N1;
    for (int i = tid; i < N1; i += 320) srow[i] = sp[i];
    __syncthreads();

    double p = 0.0;
#pragma unroll 16
    for (int h = 0; h < 64; ++h)
      p += (double)srow[h0 + h] * (double)w2s[(h0 + h) * NC + c];
    part[tid] = p;
    __syncthreads();

    if (tid < NC) {
      double y = bias;
#pragma unroll
      for (int qq = 0; qq < 8; ++qq) y += part[tid + qq * NC];
      mem = mem * 0.5 * (1.0 - spk) + y;
      spk = (mem > 1.0) ? 1.0 : 0.0;
      ssum += spk;
    }
    __syncthreads();
  }

  if (tid < NC) red[tid] = ssum;
  __syncthreads();
  if (tid < 4) {
    double s = 0.0;
#pragma unroll
    for (int i = 0; i < 10; ++i) s += red[tid * 10 + i];
    out[b * 4 + tid] = (float)(s * (1.0 / 640.0));
  }
}

extern "C" void kernel_launch(void* const* d_in, const int* in_sizes, int n_in,
                              void* d_out, int out_size, void* d_ws, size_t ws_size,
                              hipStream_t stream) {
  const float* x  = (const float*)d_in[0];   // [256, 2048, 128] == [16384, 4096]
  const float* W1 = (const float*)d_in[1];   // [4096, 512]
  const float* b1 = (const float*)d_in[2];   // [512]
  const float* W2 = (const float*)d_in[3];   // [512, 40]
  const float* b2 = (const float*)d_in[4];   // [40]
  float* out = (float*)d_out;                // [256, 4]
  float* S = (float*)d_ws;                   // spikes: 16384*512 floats = 33.5 MB

  dim3 g1(256, 8);
  gemm1_lif1<<<g1, dim3(256), 0, stream>>>(x, W1, b1, S);
  head_kernel<<<dim3(256), dim3(320), 0, stream>>>(S, W2, b2, out);
}

// Round 2
// 1579.690 us; speedup vs baseline: 1.7777x; 1.7777x over previous
//
#include <hip/hip_runtime.h>

constexpr int K1 = 4096;   // input features (32*128)
constexpr int N1 = 512;    // hidden
constexpr int TT = 64;     // time steps
constexpr int NC = 40;     // classes

// ---------------------------------------------------------------------------
// Kernel 1: h1 = x @ W1 + b1 in fp64, fused LIF1. Block tile 128x64 (M x N),
// per-thread 8x4 fp64 accumulators, K-step 32. 48 KB LDS (LIF buffer aliases
// the A tile) -> 3 blocks/CU. M=128 rows = 2 batches; LIF runs per batch.
// ---------------------------------------------------------------------------
__global__ __launch_bounds__(256, 3) void gemm1_lif1(const float* __restrict__ A,
                                                     const float* __restrict__ W1,
                                                     const float* __restrict__ b1,
                                                     float* __restrict__ S) {
  __shared__ __attribute__((aligned(16))) double lds[32 * 128 + 32 * 64]; // 48 KB
  double* const As = lds;              // [k][m], m fastest (128)
  double* const Bs = lds + 32 * 128;   // [k][n], n fastest (64)
  double* const dS = lds;              // [t][c] alias, used after GEMM

  const int tid = threadIdx.x;
  const int tx = tid & 15;             // n quad (0..15)
  const int ty = tid >> 4;             // m oct  (0..15)
  const int bm = blockIdx.y * 128;
  const int bn = blockIdx.x * 64;

  // global->LDS mappings
  const int arow = tid >> 1;           // 0..127
  const int akb  = (tid & 1) * 16;     // 0,16
  const int bkr  = tid >> 3;           // 0..31
  const int bcb  = (tid & 7) * 8;      // 0..56

  const float* Ap = A + (size_t)(bm + arow) * K1 + akb;
  const float* Bp = W1 + (size_t)bkr * N1 + bn + bcb;

  double acc[8][4] = {};
  float4 av4[4], bv4[2];

#pragma unroll
  for (int u = 0; u < 4; ++u) av4[u] = *(const float4*)(Ap + u * 4);
#pragma unroll
  for (int u = 0; u < 2; ++u) bv4[u] = *(const float4*)(Bp + u * 4);

  for (int k0 = 0; k0 < K1; k0 += 32) {
    __syncthreads();
    // stage current slice (fp32 regs -> fp64 LDS)
#pragma unroll
    for (int u = 0; u < 4; ++u) {
      As[(akb + u * 4 + 0) * 128 + arow] = (double)av4[u].x;
      As[(akb + u * 4 + 1) * 128 + arow] = (double)av4[u].y;
      As[(akb + u * 4 + 2) * 128 + arow] = (double)av4[u].z;
      As[(akb + u * 4 + 3) * 128 + arow] = (double)av4[u].w;
    }
#pragma unroll
    for (int u = 0; u < 2; ++u) {
      Bs[bkr * 64 + bcb + u * 4 + 0] = (double)bv4[u].x;
      Bs[bkr * 64 + bcb + u * 4 + 1] = (double)bv4[u].y;
      Bs[bkr * 64 + bcb + u * 4 + 2] = (double)bv4[u].z;
      Bs[bkr * 64 + bcb + u * 4 + 3] = (double)bv4[u].w;
    }
    __syncthreads();

    // prefetch next slice into registers (overlaps with compute below)
    if (k0 + 32 < K1) {
#pragma unroll
      for (int u = 0; u < 4; ++u) av4[u] = *(const float4*)(Ap + k0 + 32 + u * 4);
#pragma unroll
      for (int u = 0; u < 2; ++u) bv4[u] = *(const float4*)(Bp + (size_t)(k0 + 32) * N1 + u * 4);
    }

#pragma unroll
    for (int kk = 0; kk < 32; ++kk) {
      double a[8], w[4];
#pragma unroll
      for (int i = 0; i < 8; ++i) a[i] = As[kk * 128 + ty * 8 + i];
#pragma unroll
      for (int j = 0; j < 4; ++j) w[j] = Bs[kk * 64 + tx * 4 + j];
#pragma unroll
      for (int i = 0; i < 8; ++i)
#pragma unroll
        for (int j = 0; j < 4; ++j)
          acc[i][j] += a[i] * w[j];
    }
  }

  // Epilogue: per batch half, stage 64x64 fp64 tile and run LIF1 over t.
#pragma unroll
  for (int half = 0; half < 2; ++half) {
    __syncthreads();
    if ((ty >> 3) == half) {
      const int lr = (ty & 7) * 8;
#pragma unroll
      for (int i = 0; i < 8; ++i)
#pragma unroll
        for (int j = 0; j < 4; ++j)
          dS[(lr + i) * 64 + tx * 4 + j] = acc[i][j];
    }
    __syncthreads();
    if (tid < 64) {
      const int b = blockIdx.y * 2 + half;
      const double bias = (double)b1[bn + tid];
      double mem = 0.0, spk = 0.0;
      for (int t = 0; t < TT; ++t) {
        const double y = dS[t * 64 + tid] + bias;
        mem = mem * 0.5 * (1.0 - spk) + y;
        spk = (mem > 1.0) ? 1.0 : 0.0;
        S[((size_t)(b * TT + t)) * N1 + bn + tid] = (float)spk;
      }
    }
  }
}

// ---------------------------------------------------------------------------
// Kernel 2: per batch: y[t,c] = S[b,t,:] @ W2[:,c] + b2[c] (fp64), LIF2 state
// in registers of lanes c<40, spike-count pooling -> out[b,0..3].
// ---------------------------------------------------------------------------
__global__ __launch_bounds__(320) void head_kernel(const float* __restrict__ S,
                                                   const float* __restrict__ W2,
                                                   const float* __restrict__ b2,
                                                   float* __restrict__ out) {
  __shared__ float w2s[N1 * NC];   // 80 KB, [h][c]
  __shared__ float srow[N1];
  __shared__ double part[320];
  __shared__ double red[NC];

  const int tid = threadIdx.x;
  const int b = blockIdx.x;

  for (int i = tid; i < N1 * NC; i += 320) w2s[i] = W2[i];

  const int q  = tid / NC;    // 0..7  -> h chunk
  const int c  = tid % NC;    // class
  const int h0 = q * 64;

  double mem = 0.0, spk = 0.0, ssum = 0.0;
  const double bias = (double)b2[c];

  for (int t = 0; t < TT; ++t) {
    const float* sp = S + ((size_t)(b * TT + t)) * N1;
    for (int i = tid; i < N1; i += 320) srow[i] = sp[i];
    __syncthreads();

    double p = 0.0;
#pragma unroll 16
    for (int h = 0; h < 64; ++h)
      p += (double)srow[h0 + h] * (double)w2s[(h0 + h) * NC + c];
    part[tid] = p;
    __syncthreads();

    if (tid < NC) {
      double y = bias;
#pragma unroll
      for (int qq = 0; qq < 8; ++qq) y += part[tid + qq * NC];
      mem = mem * 0.5 * (1.0 - spk) + y;
      spk = (mem > 1.0) ? 1.0 : 0.0;
      ssum += spk;
    }
    __syncthreads();
  }

  if (tid < NC) red[tid] = ssum;
  __syncthreads();
  if (tid < 4) {
    double s = 0.0;
#pragma unroll
    for (int i = 0; i < 10; ++i) s += red[tid * 10 + i];
    out[b * 4 + tid] = (float)(s * (1.0 / 640.0));
  }
}

extern "C" void kernel_launch(void* const* d_in, const int* in_sizes, int n_in,
                              void* d_out, int out_size, void* d_ws, size_t ws_size,
                              hipStream_t stream) {
  const float* x  = (const float*)d_in[0];   // [256, 2048, 128] == [16384, 4096]
  const float* W1 = (const float*)d_in[1];   // [4096, 512]
  const float* b1 = (const float*)d_in[2];   // [512]
  const float* W2 = (const float*)d_in[3];   // [512, 40]
  const float* b2 = (const float*)d_in[4];   // [40]
  float* out = (float*)d_out;                // [256, 4]
  float* S = (float*)d_ws;                   // spikes: 16384*512 floats = 33.5 MB

  dim3 g1(8, 128);   // x = N-blocks (share A rows -> L2/L3 locality), y = M
  gemm1_lif1<<<g1, dim3(256), 0, stream>>>(x, W1, b1, S);
  head_kernel<<<dim3(256), dim3(320), 0, stream>>>(S, W2, b2, out);
}

// Round 3
// 1557.263 us; speedup vs baseline: 1.8033x; 1.0144x over previous
//
#include <hip/hip_runtime.h>

constexpr int K1 = 4096;   // input features (32*128)
constexpr int N1 = 512;    // hidden
constexpr int TT = 64;     // time steps
constexpr int NC = 40;     // classes

struct alignas(16) d2 { double x, y; };

__device__ __forceinline__ int bswz(int byteoff) {
  // XOR row bits (7..9) into bits 4..6; keeps 16B alignment.
  return byteoff ^ (((byteoff >> 7) & 7) << 4);
}

// ---------------------------------------------------------------------------
// Kernel 1: h1 = x @ W1 + b1 in fp64, fused LIF1.
// Block tile 128(M) x 128(N), K-step 32, per-thread 8x8 fp64 acc.
// LDS 64KB: As [32k][128m] fp64 (linear), Bs [32k][128n] fp64 (XOR-swizzled).
// Epilogue LIF buffer aliases the GEMM tiles. 2 blocks/CU.
// ---------------------------------------------------------------------------
__global__ __launch_bounds__(256, 2) void gemm1_lif1(const float* __restrict__ A,
                                                     const float* __restrict__ W1,
                                                     const float* __restrict__ b1,
                                                     float* __restrict__ S) {
  __shared__ __attribute__((aligned(16))) double lds[8192]; // 64 KB
  double* const As = lds;          // [k][m], m fastest (128 d = 1024 B rows)
  double* const Bs = lds + 4096;   // [k][n], n fastest, swizzled
  double* const dS = lds;          // [t][n] alias for LIF phase

  const int tid = threadIdx.x;
  const int tx = tid & 15;         // n-oct: cols tx*8..tx*8+7
  const int ty = tid >> 4;         // m-oct: rows ty*8..ty*8+7
  const int bm = blockIdx.y * 128;
  const int bn = blockIdx.x * 128;

  // staging maps
  const int arow = tid >> 1;            // 0..127 (m)
  const int akc  = (tid & 1) * 16;      // k sub-chunk 0/16
  const int brow = tid >> 3;            // 0..31 (k)
  const int bc0  = (tid & 7) * 16;      // n chunk

  const float* Ap = A + (size_t)(bm + arow) * K1 + akc;
  const float* Bp = W1 + (size_t)brow * N1 + bn + bc0;

  double acc[8][8] = {};
  float4 av[4], bv[4];

#pragma unroll
  for (int u = 0; u < 4; ++u) av[u] = *(const float4*)(Ap + u * 4);
#pragma unroll
  for (int u = 0; u < 4; ++u) bv[u] = *(const float4*)(Bp + u * 4);

  for (int k0 = 0; k0 < K1; k0 += 32) {
    __syncthreads();
    // stage A: transpose to [k][m] (scalar f64 stores, banks spread by m)
#pragma unroll
    for (int u = 0; u < 4; ++u) {
      const int k = akc + u * 4;
      As[(k + 0) * 128 + arow] = (double)av[u].x;
      As[(k + 1) * 128 + arow] = (double)av[u].y;
      As[(k + 2) * 128 + arow] = (double)av[u].z;
      As[(k + 3) * 128 + arow] = (double)av[u].w;
    }
    // stage B: [k][n] swizzled, 16B stores
#pragma unroll
    for (int u = 0; u < 4; ++u) {
      const int byte0 = brow * 1024 + bc0 * 8 + u * 32;
      *(d2*)((char*)Bs + bswz(byte0))      = d2{(double)bv[u].x, (double)bv[u].y};
      *(d2*)((char*)Bs + bswz(byte0 + 16)) = d2{(double)bv[u].z, (double)bv[u].w};
    }
    __syncthreads();

    // prefetch next K-slice into registers (hidden under FMA)
    if (k0 + 32 < K1) {
#pragma unroll
      for (int u = 0; u < 4; ++u) av[u] = *(const float4*)(Ap + k0 + 32 + u * 4);
#pragma unroll
      for (int u = 0; u < 4; ++u) bv[u] = *(const float4*)(Bp + (size_t)(k0 + 32) * N1 + u * 4);
    }

#pragma unroll 8
    for (int kk = 0; kk < 32; ++kk) {
      d2 aa[4], ww[4];
#pragma unroll
      for (int p = 0; p < 4; ++p)
        aa[p] = *(const d2*)((const char*)As + kk * 1024 + ty * 64 + p * 16);
#pragma unroll
      for (int p = 0; p < 4; ++p)
        ww[p] = *(const d2*)((const char*)Bs + bswz(kk * 1024 + tx * 64 + p * 16));
#pragma unroll
      for (int i = 0; i < 8; ++i) {
        const double a = (i & 1) ? aa[i >> 1].y : aa[i >> 1].x;
#pragma unroll
        for (int p = 0; p < 4; ++p) {
          acc[i][2 * p]     += a * ww[p].x;
          acc[i][2 * p + 1] += a * ww[p].y;
        }
      }
    }
  }

  // Epilogue: per 64-row half (one batch), stage [64t][128n] fp64, run LIF1.
#pragma unroll
  for (int half = 0; half < 2; ++half) {
    __syncthreads();
    if ((ty >> 3) == half) {
      const int lr = (ty & 7) * 8;
#pragma unroll
      for (int i = 0; i < 8; ++i)
#pragma unroll
        for (int p = 0; p < 4; ++p)
          *(d2*)((char*)dS + (lr + i) * 1024 + tx * 64 + p * 16) =
              d2{acc[i][2 * p], acc[i][2 * p + 1]};
    }
    __syncthreads();
    if (tid < 128) {
      const int b = blockIdx.y * 2 + half;
      const double bias = (double)b1[bn + tid];
      double mem = 0.0, spk = 0.0;
      for (int t = 0; t < TT; ++t) {
        const double y = dS[t * 128 + tid] + bias;
        mem = mem * 0.5 * (1.0 - spk) + y;
        spk = (mem > 1.0) ? 1.0 : 0.0;
        S[((size_t)(b * TT + t)) * N1 + bn + tid] = (float)spk;
      }
    }
  }
}

// ---------------------------------------------------------------------------
// Kernel 2: per batch: y[t,c] = S[b,t,:] @ W2[:,c] + b2[c] (fp64), LIF2 state
// in registers of lanes c<40, spike-count pooling -> out[b,0..3].
// ---------------------------------------------------------------------------
__global__ __launch_bounds__(320) void head_kernel(const float* __restrict__ S,
                                                   const float* __restrict__ W2,
                                                   const float* __restrict__ b2,
                                                   float* __restrict__ out) {
  __shared__ float w2s[N1 * NC];   // 80 KB, [h][c]
  __shared__ float srow[N1];
  __shared__ double part[320];
  __shared__ double red[NC];

  const int tid = threadIdx.x;
  const int b = blockIdx.x;

  for (int i = tid; i < N1 * NC; i += 320) w2s[i] = W2[i];

  const int q  = tid / NC;    // 0..7  -> h chunk
  const int c  = tid % NC;    // class
  const int h0 = q * 64;

  double mem = 0.0, spk = 0.0, ssum = 0.0;
  const double bias = (double)b2[c];

  for (int t = 0; t < TT; ++t) {
    const float* sp = S + ((size_t)(b * TT + t)) * N1;
    for (int i = tid; i < N1; i += 320) srow[i] = sp[i];
    __syncthreads();

    double p = 0.0;
#pragma unroll 16
    for (int h = 0; h < 64; ++h)
      p += (double)srow[h0 + h] * (double)w2s[(h0 + h) * NC + c];
    part[tid] = p;
    __syncthreads();

    if (tid < NC) {
      double y = bias;
#pragma unroll
      for (int qq = 0; qq < 8; ++qq) y += part[tid + qq * NC];
      mem = mem * 0.5 * (1.0 - spk) + y;
      spk = (mem > 1.0) ? 1.0 : 0.0;
      ssum += spk;
    }
    __syncthreads();
  }

  if (tid < NC) red[tid] = ssum;
  __syncthreads();
  if (tid < 4) {
    double s = 0.0;
#pragma unroll
    for (int i = 0; i < 10; ++i) s += red[tid * 10 + i];
    out[b * 4 + tid] = (float)(s * (1.0 / 640.0));
  }
}

extern "C" void kernel_launch(void* const* d_in, const int* in_sizes, int n_in,
                              void* d_out, int out_size, void* d_ws, size_t ws_size,
                              hipStream_t stream) {
  const float* x  = (const float*)d_in[0];   // [256, 2048, 128] == [16384, 4096]
  const float* W1 = (const float*)d_in[1];   // [4096, 512]
  const float* b1 = (const float*)d_in[2];   // [512]
  const float* W2 = (const float*)d_in[3];   // [512, 40]
  const float* b2 = (const float*)d_in[4];   // [40]
  float* out = (float*)d_out;                // [256, 4]
  float* S = (float*)d_ws;                   // spikes: 16384*512 floats = 33.5 MB

  dim3 g1(4, 128);   // x = N-blocks (share A panels), y = M-blocks
  gemm1_lif1<<<g1, dim3(256), 0, stream>>>(x, W1, b1, S);
  head_kernel<<<dim3(256), dim3(320), 0, stream>>>(S, W2, b2, out);
}

// Round 4
// 1112.867 us; speedup vs baseline: 2.5234x; 1.3993x over previous
//
#include <hip/hip_runtime.h>

typedef __bf16 bf16x8 __attribute__((ext_vector_type(8)));
typedef float f32x4 __attribute__((ext_vector_type(4)));

constexpr int K1 = 4096;
constexpr int N1 = 512;
constexpr int TT = 64;
constexpr int NC = 40;
constexpr float EPS = 2e-4f;   // flag threshold on |mem-1|; fast-path err ~6e-6 rms

// ws layout (bytes)
constexpr size_t S_OFF     = 0;                      // 16384*512 f32 = 33,554,432
constexpr size_t W1HI_OFF  = 33554432;               // [512][4096] bf16 = 4,194,304
constexpr size_t W1MID_OFF = 37748736;               // [512][4096] bf16 = 4,194,304
constexpr size_t W1T_OFF   = 41943040;               // [512][4096] f32  = 8,388,608
constexpr size_t FLAG_OFF  = 50331648;               // 256*16 u32 = 16,384

union U8 { ushort u[8]; uint4 v; };
union BC { __bf16 b; ushort s; };

// ---------------------------------------------------------------------------
// prep: W1 [4096][512] f32 -> W1hi/W1mid (bf16, transposed [n][k]) + W1T (f32,
// transposed). Runs every launch (deterministic). grid (64,8) x 256.
// ---------------------------------------------------------------------------
__global__ __launch_bounds__(256) void prep(const float* __restrict__ W1,
                                            __bf16* __restrict__ W1hi,
                                            __bf16* __restrict__ W1mid,
                                            float* __restrict__ W1T) {
  __shared__ float tile[64][65];
  const int kb = blockIdx.x * 64;
  const int nb = blockIdx.y * 64;
  const int r  = threadIdx.x >> 2;
  const int c0 = (threadIdx.x & 3) * 16;
  const float4* src = (const float4*)(W1 + (size_t)(kb + r) * N1 + nb + c0);
#pragma unroll
  for (int u = 0; u < 4; ++u) {
    float4 v = src[u];
    tile[r][c0 + u * 4 + 0] = v.x;
    tile[r][c0 + u * 4 + 1] = v.y;
    tile[r][c0 + u * 4 + 2] = v.z;
    tile[r][c0 + u * 4 + 3] = v.w;
  }
  __syncthreads();
  // write row n = nb + r, k chunk = kb + c0 .. +15
  const size_t ob = (size_t)(nb + r) * K1 + kb + c0;
  float4 of[4];
  U8 hh[2], mm[2];
#pragma unroll
  for (int u = 0; u < 4; ++u) {
    float f0 = tile[c0 + u * 4 + 0][r];
    float f1 = tile[c0 + u * 4 + 1][r];
    float f2 = tile[c0 + u * 4 + 2][r];
    float f3 = tile[c0 + u * 4 + 3][r];
    of[u] = make_float4(f0, f1, f2, f3);
    float ff[4] = {f0, f1, f2, f3};
#pragma unroll
    for (int j = 0; j < 4; ++j) {
      int idx = u * 4 + j;
      float f = ff[j];
      __bf16 h = (__bf16)f;
      __bf16 m = (__bf16)(f - (float)h);
      BC ch; ch.b = h; BC cm; cm.b = m;
      hh[idx >> 3].u[idx & 7] = ch.s;
      mm[idx >> 3].u[idx & 7] = cm.s;
    }
  }
#pragma unroll
  for (int u = 0; u < 4; ++u) *(float4*)(W1T + ob + u * 4) = of[u];
  *(uint4*)(W1hi + ob)      = hh[0].v;
  *(uint4*)(W1hi + ob + 8)  = hh[1].v;
  *(uint4*)(W1mid + ob)     = mm[0].v;
  *(uint4*)(W1mid + ob + 8) = mm[1].v;
}

// ---------------------------------------------------------------------------
// gemm_fast: 3-term bf16-split MFMA GEMM (hh + h*m + m*h), fused fp32 LIF1
// with margin flagging. Block tile 128x128, K-step 32, 4 waves (each 64x64).
// LDS 32KB: Ahi/Amid/Bhi/Bmid [128][32] bf16; epilogue reuses as [64][128] f32.
// ---------------------------------------------------------------------------
__global__ __launch_bounds__(256) void gemm_fast(const float* __restrict__ x,
                                                 const __bf16* __restrict__ W1hi,
                                                 const __bf16* __restrict__ W1mid,
                                                 const float* __restrict__ b1,
                                                 float* __restrict__ S,
                                                 unsigned* __restrict__ flags) {
  __shared__ __attribute__((aligned(16))) char lds[32768];
  char* const Ahi  = lds;
  char* const Amid = lds + 8192;
  char* const Bhi  = lds + 16384;
  char* const Bmid = lds + 24576;
  float* const dS  = (float*)lds;   // [64][128] f32, epilogue only

  const int tid = threadIdx.x;
  const int lane = tid & 63, wid = tid >> 6;
  const int wm = (wid & 1) * 64, wn = (wid >> 1) * 64;
  const int lr = lane & 15, lq = lane >> 4;
  const int bn = blockIdx.x * 128;
  const int bm = blockIdx.y * 128;

  // staging maps
  const int am = tid >> 1, akh = tid & 1;        // A: row, k-half(16)
  const int bnr = tid >> 1, bkh = tid & 1;       // B: row(n), k-half(16)

  const float* Ap = x + (size_t)(bm + am) * K1 + akh * 16;
  const __bf16* Bph = W1hi + (size_t)(bn + bnr) * K1 + bkh * 16;
  const __bf16* Bpm = W1mid + (size_t)(bn + bnr) * K1 + bkh * 16;
  const int aLdsOff = am * 64 + akh * 32;
  const int bLdsOff = bnr * 64 + bkh * 32;

  f32x4 acc[4][4] = {};
  float4 av[4];
  uint4 bvh[2], bvm[2];

#pragma unroll
  for (int u = 0; u < 4; ++u) av[u] = *(const float4*)(Ap + u * 4);
  bvh[0] = *(const uint4*)(Bph);     bvh[1] = *(const uint4*)(Bph + 8);
  bvm[0] = *(const uint4*)(Bpm);     bvm[1] = *(const uint4*)(Bpm + 8);

  for (int k0 = 0; k0 < K1; k0 += 32) {
    __syncthreads();
    // split A fp32 -> hi/mid bf16, pack, store
    U8 hA[2], mA[2];
#pragma unroll
    for (int u = 0; u < 4; ++u) {
      float ff[4] = {av[u].x, av[u].y, av[u].z, av[u].w};
#pragma unroll
      for (int j = 0; j < 4; ++j) {
        int idx = u * 4 + j;
        float f = ff[j];
        __bf16 h = (__bf16)f;
        __bf16 m = (__bf16)(f - (float)h);
        BC ch; ch.b = h; BC cm; cm.b = m;
        hA[idx >> 3].u[idx & 7] = ch.s;
        mA[idx >> 3].u[idx & 7] = cm.s;
      }
    }
    *(uint4*)(Ahi + aLdsOff)       = hA[0].v;
    *(uint4*)(Ahi + aLdsOff + 16)  = hA[1].v;
    *(uint4*)(Amid + aLdsOff)      = mA[0].v;
    *(uint4*)(Amid + aLdsOff + 16) = mA[1].v;
    *(uint4*)(Bhi + bLdsOff)       = bvh[0];
    *(uint4*)(Bhi + bLdsOff + 16)  = bvh[1];
    *(uint4*)(Bmid + bLdsOff)      = bvm[0];
    *(uint4*)(Bmid + bLdsOff + 16) = bvm[1];
    __syncthreads();

    // prefetch next K-slice
    if (k0 + 32 < K1) {
#pragma unroll
      for (int u = 0; u < 4; ++u) av[u] = *(const float4*)(Ap + k0 + 32 + u * 4);
      bvh[0] = *(const uint4*)(Bph + k0 + 32);
      bvh[1] = *(const uint4*)(Bph + k0 + 40);
      bvm[0] = *(const uint4*)(Bpm + k0 + 32);
      bvm[1] = *(const uint4*)(Bpm + k0 + 40);
    }

    // MFMA: 3 terms per output tile
    bf16x8 fbh[4], fbm[4];
#pragma unroll
    for (int nt = 0; nt < 4; ++nt) {
      const int off = (wn + nt * 16 + lr) * 64 + lq * 16;
      fbh[nt] = *(const bf16x8*)(Bhi + off);
      fbm[nt] = *(const bf16x8*)(Bmid + off);
    }
#pragma unroll
    for (int mt = 0; mt < 4; ++mt) {
      const int off = (wm + mt * 16 + lr) * 64 + lq * 16;
      bf16x8 fah = *(const bf16x8*)(Ahi + off);
      bf16x8 fam = *(const bf16x8*)(Amid + off);
#pragma unroll
      for (int nt = 0; nt < 4; ++nt) {
        acc[mt][nt] = __builtin_amdgcn_mfma_f32_16x16x32_bf16(fam, fbh[nt], acc[mt][nt], 0, 0, 0);
        acc[mt][nt] = __builtin_amdgcn_mfma_f32_16x16x32_bf16(fah, fbm[nt], acc[mt][nt], 0, 0, 0);
        acc[mt][nt] = __builtin_amdgcn_mfma_f32_16x16x32_bf16(fah, fbh[nt], acc[mt][nt], 0, 0, 0);
      }
    }
  }

  // Epilogue: per 64-row half (one batch), stage y f32, fp32 LIF1 + flagging.
#pragma unroll
  for (int half = 0; half < 2; ++half) {
    __syncthreads();
    if ((wid & 1) == half) {
#pragma unroll
      for (int mt = 0; mt < 4; ++mt)
#pragma unroll
        for (int nt = 0; nt < 4; ++nt)
#pragma unroll
          for (int r = 0; r < 4; ++r)
            dS[(mt * 16 + lq * 4 + r) * 128 + wn + nt * 16 + lr] = acc[mt][nt][r];
    }
    __syncthreads();
    if (tid < 128) {
      const int n = tid;
      const int b = blockIdx.y * 2 + half;
      const float bias = b1[bn + n];
      float mem = 0.0f, spk = 0.0f, mn = 1e9f;
      for (int t = 0; t < TT; ++t) {
        const float y = dS[t * 128 + n] + bias;
        mem = mem * 0.5f * (1.0f - spk) + y;
        const float d = mem - 1.0f;
        mn = fminf(mn, fabsf(d));
        spk = (d > 0.0f) ? 1.0f : 0.0f;
        S[((size_t)(b * TT + t)) * N1 + bn + n] = spk;
      }
      if (mn < EPS)
        atomicOr(flags + (b * 16 + ((bn + n) >> 5)), 1u << ((bn + n) & 31));
    }
  }
}

// ---------------------------------------------------------------------------
// fixup: for each flagged (b,n) trajectory, recompute y in fp64 and redo LIF1,
// overwriting S. grid 256 (one block per b) x 256 threads.
// ---------------------------------------------------------------------------
__global__ __launch_bounds__(256) void fixup(const float* __restrict__ x,
                                             const float* __restrict__ W1T,
                                             const float* __restrict__ b1,
                                             const unsigned* __restrict__ flags,
                                             float* __restrict__ S) {
  __shared__ int nlist[512];
  __shared__ int ncnt;
  __shared__ double yrow[64];
  const int b = blockIdx.x;
  const int tid = threadIdx.x;

  if (tid == 0) {
    int c = 0;
    for (int w = 0; w < 16; ++w) {
      unsigned f = flags[b * 16 + w];
      while (f) {
        int bit = __ffs(f) - 1;
        f &= f - 1;
        nlist[c++] = w * 32 + bit;
      }
    }
    ncnt = c;
  }
  __syncthreads();
  const int cnt = ncnt;

  const int t = tid >> 2, q = tid & 3;
  for (int ii = 0; ii < cnt; ++ii) {
    const int n = nlist[ii];
    const float* xr = x + ((size_t)(b * TT + t)) * K1 + q * 1024;
    const float* wr = W1T + (size_t)n * K1 + q * 1024;
    double p0 = 0, p1 = 0, p2 = 0, p3 = 0;
    for (int j = 0; j < 1024; j += 4) {
      p0 += (double)xr[j + 0] * (double)wr[j + 0];
      p1 += (double)xr[j + 1] * (double)wr[j + 1];
      p2 += (double)xr[j + 2] * (double)wr[j + 2];
      p3 += (double)xr[j + 3] * (double)wr[j + 3];
    }
    double p = (p0 + p1) + (p2 + p3);
    p += __shfl_xor(p, 1);
    p += __shfl_xor(p, 2);
    if (q == 0) yrow[t] = p;
    __syncthreads();
    if (tid == 0) {
      double mem = 0.0, spk = 0.0;
      const double bias = (double)b1[n];
      for (int t2 = 0; t2 < TT; ++t2) {
        const double y = yrow[t2] + bias;
        mem = mem * 0.5 * (1.0 - spk) + y;
        spk = (mem > 1.0) ? 1.0 : 0.0;
        S[((size_t)(b * TT + t2)) * N1 + n] = (float)spk;
      }
    }
    __syncthreads();
  }
}

// ---------------------------------------------------------------------------
// head: exact fp64 GEMM2 + LIF2 + pooling (unchanged from R3).
// ---------------------------------------------------------------------------
__global__ __launch_bounds__(320) void head_kernel(const float* __restrict__ S,
                                                   const float* __restrict__ W2,
                                                   const float* __restrict__ b2,
                                                   float* __restrict__ out) {
  __shared__ float w2s[N1 * NC];
  __shared__ float srow[N1];
  __shared__ double part[320];
  __shared__ double red[NC];

  const int tid = threadIdx.x;
  const int b = blockIdx.x;

  for (int i = tid; i < N1 * NC; i += 320) w2s[i] = W2[i];

  const int q  = tid / NC;
  const int c  = tid % NC;
  const int h0 = q * 64;

  double mem = 0.0, spk = 0.0, ssum = 0.0;
  const double bias = (double)b2[c];

  for (int t = 0; t < TT; ++t) {
    const float* sp = S + ((size_t)(b * TT + t)) * N1;
    for (int i = tid; i < N1; i += 320) srow[i] = sp[i];
    __syncthreads();

    double p = 0.0;
#pragma unroll 16
    for (int h = 0; h < 64; ++h)
      p += (double)srow[h0 + h] * (double)w2s[(h0 + h) * NC + c];
    part[tid] = p;
    __syncthreads();

    if (tid < NC) {
      double y = bias;
#pragma unroll
      for (int qq = 0; qq < 8; ++qq) y += part[tid + qq * NC];
      mem = mem * 0.5 * (1.0 - spk) + y;
      spk = (mem > 1.0) ? 1.0 : 0.0;
      ssum += spk;
    }
    __syncthreads();
  }

  if (tid < NC) red[tid] = ssum;
  __syncthreads();
  if (tid < 4) {
    double s = 0.0;
#pragma unroll
    for (int i = 0; i < 10; ++i) s += red[tid * 10 + i];
    out[b * 4 + tid] = (float)(s * (1.0 / 640.0));
  }
}

extern "C" void kernel_launch(void* const* d_in, const int* in_sizes, int n_in,
                              void* d_out, int out_size, void* d_ws, size_t ws_size,
                              hipStream_t stream) {
  const float* x  = (const float*)d_in[0];
  const float* W1 = (const float*)d_in[1];
  const float* b1 = (const float*)d_in[2];
  const float* W2 = (const float*)d_in[3];
  const float* b2 = (const float*)d_in[4];
  float* out = (float*)d_out;

  char* ws = (char*)d_ws;
  float*    Sb    = (float*)(ws + S_OFF);
  __bf16*   W1hi  = (__bf16*)(ws + W1HI_OFF);
  __bf16*   W1mid = (__bf16*)(ws + W1MID_OFF);
  float*    W1T   = (float*)(ws + W1T_OFF);
  unsigned* flags = (unsigned*)(ws + FLAG_OFF);

  hipMemsetAsync(flags, 0, 16384, stream);
  prep<<<dim3(64, 8), dim3(256), 0, stream>>>(W1, W1hi, W1mid, W1T);
  gemm_fast<<<dim3(4, 128), dim3(256), 0, stream>>>(x, W1hi, W1mid, b1, Sb, flags);
  fixup<<<dim3(256), dim3(256), 0, stream>>>(x, W1T, b1, flags, Sb);
  head_kernel<<<dim3(256), dim3(320), 0, stream>>>(Sb, W2, b2, out);
}

// Round 5
// 916.252 us; speedup vs baseline: 3.0649x; 1.2146x over previous
//
#include <hip/hip_runtime.h>

typedef __bf16 bf16x8 __attribute__((ext_vector_type(8)));
typedef float f32x16 __attribute__((ext_vector_type(16)));

constexpr int K1 = 4096;
constexpr int N1 = 512;
constexpr int TT = 64;
constexpr int NC = 40;
constexpr float EPS = 2e-4f;   // flag threshold on |mem-1|; fast-path err ~5e-6 rms

// ws layout (bytes)
constexpr size_t S_OFF     = 0;                      // 16384*512 f32 = 33,554,432
constexpr size_t W1HI_OFF  = 33554432;               // [512][4096] bf16
constexpr size_t W1MID_OFF = 37748736;               // [512][4096] bf16
constexpr size_t W1T_OFF   = 41943040;               // [512][4096] f32
constexpr size_t FLAG_OFF  = 50331648;               // 256*16 u32

union U8 { ushort u[8]; uint4 v; };
union BC { __bf16 b; ushort s; };

// ---------------------------------------------------------------------------
// prep: W1 [4096][512] f32 -> W1hi/W1mid (bf16, [n][k]) + W1T (f32, [n][k]).
// ---------------------------------------------------------------------------
__global__ __launch_bounds__(256) void prep(const float* __restrict__ W1,
                                            __bf16* __restrict__ W1hi,
                                            __bf16* __restrict__ W1mid,
                                            float* __restrict__ W1T) {
  __shared__ float tile[64][65];
  const int kb = blockIdx.x * 64;
  const int nb = blockIdx.y * 64;
  const int r  = threadIdx.x >> 2;
  const int c0 = (threadIdx.x & 3) * 16;
  const float4* src = (const float4*)(W1 + (size_t)(kb + r) * N1 + nb + c0);
#pragma unroll
  for (int u = 0; u < 4; ++u) {
    float4 v = src[u];
    tile[r][c0 + u * 4 + 0] = v.x;
    tile[r][c0 + u * 4 + 1] = v.y;
    tile[r][c0 + u * 4 + 2] = v.z;
    tile[r][c0 + u * 4 + 3] = v.w;
  }
  __syncthreads();
  const size_t ob = (size_t)(nb + r) * K1 + kb + c0;
  float4 of[4];
  U8 hh[2], mm[2];
#pragma unroll
  for (int u = 0; u < 4; ++u) {
    float f0 = tile[c0 + u * 4 + 0][r];
    float f1 = tile[c0 + u * 4 + 1][r];
    float f2 = tile[c0 + u * 4 + 2][r];
    float f3 = tile[c0 + u * 4 + 3][r];
    of[u] = make_float4(f0, f1, f2, f3);
    float ff[4] = {f0, f1, f2, f3};
#pragma unroll
    for (int j = 0; j < 4; ++j) {
      int idx = u * 4 + j;
      float f = ff[j];
      __bf16 h = (__bf16)f;
      __bf16 m = (__bf16)(f - (float)h);
      BC ch; ch.b = h; BC cm; cm.b = m;
      hh[idx >> 3].u[idx & 7] = ch.s;
      mm[idx >> 3].u[idx & 7] = cm.s;
    }
  }
#pragma unroll
  for (int u = 0; u < 4; ++u) *(float4*)(W1T + ob + u * 4) = of[u];
  *(uint4*)(W1hi + ob)      = hh[0].v;
  *(uint4*)(W1hi + ob + 8)  = hh[1].v;
  *(uint4*)(W1mid + ob)     = mm[0].v;
  *(uint4*)(W1mid + ob + 8) = mm[1].v;
}

// ---------------------------------------------------------------------------
// gemm_fast: 3-term bf16-split via 32x32x16 MFMA, fused fp32 LIF1 + flagging.
// Block 128M x 64N, BK=32, 4 waves (wave tile 64M x 32N, 2 m-subtiles of 32).
// LDS rows padded to 80B -> all b128 frag reads/writes hit the 8-quad minimum.
// Grid 8x128 = 1024 blocks = 4/CU; XCD swizzle gives each XCD an m-stripe.
// ---------------------------------------------------------------------------
__global__ __launch_bounds__(256, 4) void gemm_fast(const float* __restrict__ x,
                                                    const __bf16* __restrict__ W1hi,
                                                    const __bf16* __restrict__ W1mid,
                                                    const float* __restrict__ b1,
                                                    float* __restrict__ S,
                                                    unsigned* __restrict__ flags) {
  __shared__ __attribute__((aligned(16))) char lds[30720];
  char* const Ahi  = lds;            // [128][32] bf16, 80B rows = 10240
  char* const Amid = lds + 10240;
  char* const Bhi  = lds + 20480;    // [64][32] bf16, 80B rows = 5120
  char* const Bmid = lds + 25600;
  float* const dS  = (float*)lds;    // [64 t][64 n] f32, epilogue alias

  const int tid = threadIdx.x;
  const int lane = tid & 63, wid = tid >> 6;
  const int lr = lane & 31, lhi = lane >> 5;
  const int wm = (wid & 1) * 64, wn = (wid >> 1) * 32;

  // XCD-aware swizzle: id%8 ~ XCD; give each XCD a contiguous m-stripe so the
  // 8 n-blocks sharing an A-panel run on one XCD (panel hits its L2 once).
  const int id = blockIdx.y * 8 + blockIdx.x;
  const int xcd = id & 7, sq = id >> 3;
  const int m_blk = xcd * 16 + (sq >> 3);
  const int n_blk = sq & 7;
  const int bm = m_blk * 128, bn = n_blk * 64;

  // staging maps
  const int ar = tid >> 1, ak = (tid & 1) * 16;   // A: row 0..127, k-off 0/16
  const int br = tid >> 2, bj = (tid & 3) * 8;    // B: row 0..63, k-off 0..24

  const float* Ap = x + (size_t)(bm + ar) * K1 + ak;
  const __bf16* Bph = W1hi + (size_t)(bn + br) * K1 + bj;
  const __bf16* Bpm = W1mid + (size_t)(bn + br) * K1 + bj;
  const int aoff = ar * 80 + ak * 2;
  const int boff = br * 80 + bj * 2;

  f32x16 acc[2] = {};
  float4 av[4];
  uint4 bvh, bvm;

#pragma unroll
  for (int u = 0; u < 4; ++u) av[u] = *(const float4*)(Ap + u * 4);
  bvh = *(const uint4*)Bph;
  bvm = *(const uint4*)Bpm;

  for (int k0 = 0; k0 < K1; k0 += 32) {
    __syncthreads();
    // split A fp32 -> hi/mid bf16 and stage all tiles
    U8 hA[2], mA[2];
#pragma unroll
    for (int u = 0; u < 4; ++u) {
      float ff[4] = {av[u].x, av[u].y, av[u].z, av[u].w};
#pragma unroll
      for (int j = 0; j < 4; ++j) {
        int idx = u * 4 + j;
        float f = ff[j];
        __bf16 h = (__bf16)f;
        __bf16 m = (__bf16)(f - (float)h);
        BC ch; ch.b = h; BC cm; cm.b = m;
        hA[idx >> 3].u[idx & 7] = ch.s;
        mA[idx >> 3].u[idx & 7] = cm.s;
      }
    }
    *(uint4*)(Ahi + aoff)       = hA[0].v;
    *(uint4*)(Ahi + aoff + 16)  = hA[1].v;
    *(uint4*)(Amid + aoff)      = mA[0].v;
    *(uint4*)(Amid + aoff + 16) = mA[1].v;
    *(uint4*)(Bhi + boff)       = bvh;
    *(uint4*)(Bmid + boff)      = bvm;
    __syncthreads();

    // prefetch next K-slice
    if (k0 + 32 < K1) {
#pragma unroll
      for (int u = 0; u < 4; ++u) av[u] = *(const float4*)(Ap + k0 + 32 + u * 4);
      bvh = *(const uint4*)(Bph + k0 + 32);
      bvm = *(const uint4*)(Bpm + k0 + 32);
    }

    // MFMA: per k-half, 2 m-subtiles x 3 terms
#pragma unroll
    for (int kh = 0; kh < 2; ++kh) {
      const int fo = kh * 32 + lhi * 16;
      bf16x8 bh = *(const bf16x8*)(Bhi + (wn + lr) * 80 + fo);
      bf16x8 bm_ = *(const bf16x8*)(Bmid + (wn + lr) * 80 + fo);
#pragma unroll
      for (int mt = 0; mt < 2; ++mt) {
        const int ao = (wm + mt * 32 + lr) * 80 + fo;
        bf16x8 ah = *(const bf16x8*)(Ahi + ao);
        bf16x8 am_ = *(const bf16x8*)(Amid + ao);
        acc[mt] = __builtin_amdgcn_mfma_f32_32x32x16_bf16(am_, bh, acc[mt], 0, 0, 0);
        acc[mt] = __builtin_amdgcn_mfma_f32_32x32x16_bf16(ah, bm_, acc[mt], 0, 0, 0);
        acc[mt] = __builtin_amdgcn_mfma_f32_32x32x16_bf16(ah, bh, acc[mt], 0, 0, 0);
      }
    }
  }

  // Epilogue: per 64-row half (one batch), stage y f32, fp32 LIF1 + flagging.
#pragma unroll
  for (int half = 0; half < 2; ++half) {
    __syncthreads();
    if ((wid & 1) == half) {
#pragma unroll
      for (int mt = 0; mt < 2; ++mt)
#pragma unroll
        for (int r = 0; r < 16; ++r) {
          const int row = mt * 32 + (r & 3) + 8 * (r >> 2) + 4 * lhi;
          dS[row * 64 + wn + lr] = acc[mt][r];
        }
    }
    __syncthreads();
    if (tid < 64) {
      const int n = tid;
      const int b = m_blk * 2 + half;
      const float bias = b1[bn + n];
      float mem = 0.0f, spk = 0.0f, mn = 1e9f;
      for (int t = 0; t < TT; ++t) {
        const float y = dS[t * 64 + n] + bias;
        mem = mem * 0.5f * (1.0f - spk) + y;
        const float d = mem - 1.0f;
        mn = fminf(mn, fabsf(d));
        spk = (d > 0.0f) ? 1.0f : 0.0f;
        S[((size_t)(b * TT + t)) * N1 + bn + n] = spk;
      }
      if (mn < EPS)
        atomicOr(flags + (b * 16 + ((bn + n) >> 5)), 1u << ((bn + n) & 31));
    }
  }
}

// ---------------------------------------------------------------------------
// fixup: recompute flagged (b,n) trajectories in fp64, overwrite S.
// ---------------------------------------------------------------------------
__global__ __launch_bounds__(256) void fixup(const float* __restrict__ x,
                                             const float* __restrict__ W1T,
                                             const float* __restrict__ b1,
                                             const unsigned* __restrict__ flags,
                                             float* __restrict__ S) {
  __shared__ int nlist[512];
  __shared__ int ncnt;
  __shared__ double yrow[64];
  const int b = blockIdx.x;
  const int tid = threadIdx.x;

  if (tid == 0) {
    int c = 0;
    for (int w = 0; w < 16; ++w) {
      unsigned f = flags[b * 16 + w];
      while (f) {
        int bit = __ffs(f) - 1;
        f &= f - 1;
        nlist[c++] = w * 32 + bit;
      }
    }
    ncnt = c;
  }
  __syncthreads();
  const int cnt = ncnt;

  const int t = tid >> 2, q = tid & 3;
  for (int ii = 0; ii < cnt; ++ii) {
    const int n = nlist[ii];
    const float* xr = x + ((size_t)(b * TT + t)) * K1 + q * 1024;
    const float* wr = W1T + (size_t)n * K1 + q * 1024;
    double p0 = 0, p1 = 0, p2 = 0, p3 = 0;
    for (int j = 0; j < 1024; j += 4) {
      p0 += (double)xr[j + 0] * (double)wr[j + 0];
      p1 += (double)xr[j + 1] * (double)wr[j + 1];
      p2 += (double)xr[j + 2] * (double)wr[j + 2];
      p3 += (double)xr[j + 3] * (double)wr[j + 3];
    }
    double p = (p0 + p1) + (p2 + p3);
    p += __shfl_xor(p, 1);
    p += __shfl_xor(p, 2);
    if (q == 0) yrow[t] = p;
    __syncthreads();
    if (tid == 0) {
      double mem = 0.0, spk = 0.0;
      const double bias = (double)b1[n];
      for (int t2 = 0; t2 < TT; ++t2) {
        const double y = yrow[t2] + bias;
        mem = mem * 0.5 * (1.0 - spk) + y;
        spk = (mem > 1.0) ? 1.0 : 0.0;
        S[((size_t)(b * TT + t2)) * N1 + n] = (float)spk;
      }
    }
    __syncthreads();
  }
}

// ---------------------------------------------------------------------------
// head: exact fp64 GEMM2 + LIF2 + pooling.
// ---------------------------------------------------------------------------
__global__ __launch_bounds__(320) void head_kernel(const float* __restrict__ S,
                                                   const float* __restrict__ W2,
                                                   const float* __restrict__ b2,
                                                   float* __restrict__ out) {
  __shared__ float w2s[N1 * NC];
  __shared__ float srow[N1];
  __shared__ double part[320];
  __shared__ double red[NC];

  const int tid = threadIdx.x;
  const int b = blockIdx.x;

  for (int i = tid; i < N1 * NC; i += 320) w2s[i] = W2[i];

  const int q  = tid / NC;
  const int c  = tid % NC;
  const int h0 = q * 64;

  double mem = 0.0, spk = 0.0, ssum = 0.0;
  const double bias = (double)b2[c];

  for (int t = 0; t < TT; ++t) {
    const float* sp = S + ((size_t)(b * TT + t)) * N1;
    for (int i = tid; i < N1; i += 320) srow[i] = sp[i];
    __syncthreads();

    double p = 0.0;
#pragma unroll 16
    for (int h = 0; h < 64; ++h)
      p += (double)srow[h0 + h] * (double)w2s[(h0 + h) * NC + c];
    part[tid] = p;
    __syncthreads();

    if (tid < NC) {
      double y = bias;
#pragma unroll
      for (int qq = 0; qq < 8; ++qq) y += part[tid + qq * NC];
      mem = mem * 0.5 * (1.0 - spk) + y;
      spk = (mem > 1.0) ? 1.0 : 0.0;
      ssum += spk;
    }
    __syncthreads();
  }

  if (tid < NC) red[tid] = ssum;
  __syncthreads();
  if (tid < 4) {
    double s = 0.0;
#pragma unroll
    for (int i = 0; i < 10; ++i) s += red[tid * 10 + i];
    out[b * 4 + tid] = (float)(s * (1.0 / 640.0));
  }
}

extern "C" void kernel_launch(void* const* d_in, const int* in_sizes, int n_in,
                              void* d_out, int out_size, void* d_ws, size_t ws_size,
                              hipStream_t stream) {
  const float* x  = (const float*)d_in[0];
  const float* W1 = (const float*)d_in[1];
  const float* b1 = (const float*)d_in[2];
  const float* W2 = (const float*)d_in[3];
  const float* b2 = (const float*)d_in[4];
  float* out = (float*)d_out;

  char* ws = (char*)d_ws;
  float*    Sb    = (float*)(ws + S_OFF);
  __bf16*   W1hi  = (__bf16*)(ws + W1HI_OFF);
  __bf16*   W1mid = (__bf16*)(ws + W1MID_OFF);
  float*    W1T   = (float*)(ws + W1T_OFF);
  unsigned* flags = (unsigned*)(ws + FLAG_OFF);

  hipMemsetAsync(flags, 0, 16384, stream);
  prep<<<dim3(64, 8), dim3(256), 0, stream>>>(W1, W1hi, W1mid, W1T);
  gemm_fast<<<dim3(8, 128), dim3(256), 0, stream>>>(x, W1hi, W1mid, b1, Sb, flags);
  fixup<<<dim3(256), dim3(256), 0, stream>>>(x, W1T, b1, flags, Sb);
  head_kernel<<<dim3(256), dim3(320), 0, stream>>>(Sb, W2, b2, out);
}

// Round 6
// 526.087 us; speedup vs baseline: 5.3379x; 1.7416x over previous
//
#include <hip/hip_runtime.h>

typedef __bf16 bf16x8 __attribute__((ext_vector_type(8)));
typedef float f32x16 __attribute__((ext_vector_type(16)));

constexpr int K1 = 4096;
constexpr int N1 = 512;
constexpr int TT = 64;
constexpr int NC = 40;
constexpr float EPS = 2e-4f;   // flag threshold on |mem-1|; fast-path err ~5e-6 rms
constexpr unsigned CAP = 32768;

// ws layout (bytes)
constexpr size_t S_OFF     = 0;                      // 16384*512 f32 = 33,554,432
constexpr size_t W1HI_OFF  = 33554432;               // [512][4096] bf16
constexpr size_t W1MID_OFF = 37748736;               // [512][4096] bf16
constexpr size_t W1T_OFF   = 41943040;               // [512][4096] f32
constexpr size_t CNT_OFF   = 50331648;               // u32 count (256B slot)
constexpr size_t LIST_OFF  = 50331904;               // CAP u32 entries

union U8 { ushort u[8]; uint4 v; };
union BC { __bf16 b; ushort s; };

// ---------------------------------------------------------------------------
// prep: W1 [4096][512] f32 -> W1hi/W1mid (bf16, [n][k]) + W1T (f32, [n][k]).
// ---------------------------------------------------------------------------
__global__ __launch_bounds__(256) void prep(const float* __restrict__ W1,
                                            __bf16* __restrict__ W1hi,
                                            __bf16* __restrict__ W1mid,
                                            float* __restrict__ W1T) {
  __shared__ float tile[64][65];
  const int kb = blockIdx.x * 64;
  const int nb = blockIdx.y * 64;
  const int r  = threadIdx.x >> 2;
  const int c0 = (threadIdx.x & 3) * 16;
  const float4* src = (const float4*)(W1 + (size_t)(kb + r) * N1 + nb + c0);
#pragma unroll
  for (int u = 0; u < 4; ++u) {
    float4 v = src[u];
    tile[r][c0 + u * 4 + 0] = v.x;
    tile[r][c0 + u * 4 + 1] = v.y;
    tile[r][c0 + u * 4 + 2] = v.z;
    tile[r][c0 + u * 4 + 3] = v.w;
  }
  __syncthreads();
  const size_t ob = (size_t)(nb + r) * K1 + kb + c0;
  float4 of[4];
  U8 hh[2], mm[2];
#pragma unroll
  for (int u = 0; u < 4; ++u) {
    float f0 = tile[c0 + u * 4 + 0][r];
    float f1 = tile[c0 + u * 4 + 1][r];
    float f2 = tile[c0 + u * 4 + 2][r];
    float f3 = tile[c0 + u * 4 + 3][r];
    of[u] = make_float4(f0, f1, f2, f3);
    float ff[4] = {f0, f1, f2, f3};
#pragma unroll
    for (int j = 0; j < 4; ++j) {
      int idx = u * 4 + j;
      float f = ff[j];
      __bf16 h = (__bf16)f;
      __bf16 m = (__bf16)(f - (float)h);
      BC ch; ch.b = h; BC cm; cm.b = m;
      hh[idx >> 3].u[idx & 7] = ch.s;
      mm[idx >> 3].u[idx & 7] = cm.s;
    }
  }
#pragma unroll
  for (int u = 0; u < 4; ++u) *(float4*)(W1T + ob + u * 4) = of[u];
  *(uint4*)(W1hi + ob)      = hh[0].v;
  *(uint4*)(W1hi + ob + 8)  = hh[1].v;
  *(uint4*)(W1mid + ob)     = mm[0].v;
  *(uint4*)(W1mid + ob + 8) = mm[1].v;
}

// ---------------------------------------------------------------------------
// gemm_fast: 3-term bf16-split via 32x32x16 MFMA, fused fp32 LIF1.
// Flagged (b,n) trajectories are appended to a global entry list.
// ---------------------------------------------------------------------------
__global__ __launch_bounds__(256, 4) void gemm_fast(const float* __restrict__ x,
                                                    const __bf16* __restrict__ W1hi,
                                                    const __bf16* __restrict__ W1mid,
                                                    const float* __restrict__ b1,
                                                    float* __restrict__ S,
                                                    unsigned* __restrict__ cnt,
                                                    unsigned* __restrict__ list) {
  __shared__ __attribute__((aligned(16))) char lds[30720];
  char* const Ahi  = lds;            // [128][32] bf16, 80B rows
  char* const Amid = lds + 10240;
  char* const Bhi  = lds + 20480;    // [64][32] bf16, 80B rows
  char* const Bmid = lds + 25600;
  float* const dS  = (float*)lds;    // [64 t][64 n] f32, epilogue alias

  const int tid = threadIdx.x;
  const int lane = tid & 63, wid = tid >> 6;
  const int lr = lane & 31, lhi = lane >> 5;
  const int wm = (wid & 1) * 64, wn = (wid >> 1) * 32;

  const int id = blockIdx.y * 8 + blockIdx.x;
  const int xcd = id & 7, sq = id >> 3;
  const int m_blk = xcd * 16 + (sq >> 3);
  const int n_blk = sq & 7;
  const int bm = m_blk * 128, bn = n_blk * 64;

  const int ar = tid >> 1, ak = (tid & 1) * 16;
  const int br = tid >> 2, bj = (tid & 3) * 8;

  const float* Ap = x + (size_t)(bm + ar) * K1 + ak;
  const __bf16* Bph = W1hi + (size_t)(bn + br) * K1 + bj;
  const __bf16* Bpm = W1mid + (size_t)(bn + br) * K1 + bj;
  const int aoff = ar * 80 + ak * 2;
  const int boff = br * 80 + bj * 2;

  f32x16 acc[2] = {};
  float4 av[4];
  uint4 bvh, bvm;

#pragma unroll
  for (int u = 0; u < 4; ++u) av[u] = *(const float4*)(Ap + u * 4);
  bvh = *(const uint4*)Bph;
  bvm = *(const uint4*)Bpm;

  for (int k0 = 0; k0 < K1; k0 += 32) {
    __syncthreads();
    U8 hA[2], mA[2];
#pragma unroll
    for (int u = 0; u < 4; ++u) {
      float ff[4] = {av[u].x, av[u].y, av[u].z, av[u].w};
#pragma unroll
      for (int j = 0; j < 4; ++j) {
        int idx = u * 4 + j;
        float f = ff[j];
        __bf16 h = (__bf16)f;
        __bf16 m = (__bf16)(f - (float)h);
        BC ch; ch.b = h; BC cm; cm.b = m;
        hA[idx >> 3].u[idx & 7] = ch.s;
        mA[idx >> 3].u[idx & 7] = cm.s;
      }
    }
    *(uint4*)(Ahi + aoff)       = hA[0].v;
    *(uint4*)(Ahi + aoff + 16)  = hA[1].v;
    *(uint4*)(Amid + aoff)      = mA[0].v;
    *(uint4*)(Amid + aoff + 16) = mA[1].v;
    *(uint4*)(Bhi + boff)       = bvh;
    *(uint4*)(Bmid + boff)      = bvm;
    __syncthreads();

    if (k0 + 32 < K1) {
#pragma unroll
      for (int u = 0; u < 4; ++u) av[u] = *(const float4*)(Ap + k0 + 32 + u * 4);
      bvh = *(const uint4*)(Bph + k0 + 32);
      bvm = *(const uint4*)(Bpm + k0 + 32);
    }

#pragma unroll
    for (int kh = 0; kh < 2; ++kh) {
      const int fo = kh * 32 + lhi * 16;
      bf16x8 bh = *(const bf16x8*)(Bhi + (wn + lr) * 80 + fo);
      bf16x8 bm_ = *(const bf16x8*)(Bmid + (wn + lr) * 80 + fo);
#pragma unroll
      for (int mt = 0; mt < 2; ++mt) {
        const int ao = (wm + mt * 32 + lr) * 80 + fo;
        bf16x8 ah = *(const bf16x8*)(Ahi + ao);
        bf16x8 am_ = *(const bf16x8*)(Amid + ao);
        acc[mt] = __builtin_amdgcn_mfma_f32_32x32x16_bf16(am_, bh, acc[mt], 0, 0, 0);
        acc[mt] = __builtin_amdgcn_mfma_f32_32x32x16_bf16(ah, bm_, acc[mt], 0, 0, 0);
        acc[mt] = __builtin_amdgcn_mfma_f32_32x32x16_bf16(ah, bh, acc[mt], 0, 0, 0);
      }
    }
  }

#pragma unroll
  for (int half = 0; half < 2; ++half) {
    __syncthreads();
    if ((wid & 1) == half) {
#pragma unroll
      for (int mt = 0; mt < 2; ++mt)
#pragma unroll
        for (int r = 0; r < 16; ++r) {
          const int row = mt * 32 + (r & 3) + 8 * (r >> 2) + 4 * lhi;
          dS[row * 64 + wn + lr] = acc[mt][r];
        }
    }
    __syncthreads();
    if (tid < 64) {
      const int n = tid;
      const int b = m_blk * 2 + half;
      const float bias = b1[bn + n];
      float mem = 0.0f, spk = 0.0f, mn = 1e9f;
      for (int t = 0; t < TT; ++t) {
        const float y = dS[t * 64 + n] + bias;
        mem = mem * 0.5f * (1.0f - spk) + y;
        const float d = mem - 1.0f;
        mn = fminf(mn, fabsf(d));
        spk = (d > 0.0f) ? 1.0f : 0.0f;
        S[((size_t)(b * TT + t)) * N1 + bn + n] = spk;
      }
      if (mn < EPS) {
        unsigned idx = atomicAdd(cnt, 1u);
        if (idx < CAP) list[idx] = ((unsigned)b << 16) | (unsigned)(bn + n);
      }
    }
  }
}

// ---------------------------------------------------------------------------
// fixup: grid-stride over flagged entries; one block per entry; one wave per
// timestep group (wave w -> t = w*16..w*16+15); lane-l float4 reads are fully
// coalesced (1KB contiguous per wave-load). fp64 dot + butterfly reduce,
// thread 0 replays the LIF in fp64 and overwrites S.
// ---------------------------------------------------------------------------
__global__ __launch_bounds__(256) void fixup(const float* __restrict__ x,
                                             const float* __restrict__ W1T,
                                             const float* __restrict__ b1,
                                             const unsigned* __restrict__ cnt,
                                             const unsigned* __restrict__ list,
                                             float* __restrict__ S) {
  __shared__ double yrow[TT];
  const int tid = threadIdx.x;
  const int lane = tid & 63, w = tid >> 6;
  const int count = (int)min(*cnt, CAP);

  for (int e = blockIdx.x; e < count; e += gridDim.x) {
    const unsigned ent = list[e];
    const int b = (int)(ent >> 16), n = (int)(ent & 0xffffu);
    const float4* wr = (const float4*)(W1T + (size_t)n * K1);
#pragma unroll 1
    for (int i = 0; i < 16; ++i) {
      const int t = w * 16 + i;
      const float4* xr = (const float4*)(x + ((size_t)(b * TT + t)) * K1);
      double p = 0.0;
#pragma unroll
      for (int j = 0; j < 16; ++j) {
        const float4 xv = xr[lane + 64 * j];
        const float4 wv = wr[lane + 64 * j];
        p += (double)xv.x * (double)wv.x + (double)xv.y * (double)wv.y +
             (double)xv.z * (double)wv.z + (double)xv.w * (double)wv.w;
      }
#pragma unroll
      for (int off = 1; off < 64; off <<= 1) p += __shfl_xor(p, off);
      if (lane == 0) yrow[t] = p;
    }
    __syncthreads();
    if (tid == 0) {
      double mem = 0.0, spk = 0.0;
      const double bias = (double)b1[n];
      for (int t2 = 0; t2 < TT; ++t2) {
        const double y = yrow[t2] + bias;
        mem = mem * 0.5 * (1.0 - spk) + y;
        spk = (mem > 1.0) ? 1.0 : 0.0;
        S[((size_t)(b * TT + t2)) * N1 + n] = (float)spk;
      }
    }
    __syncthreads();
  }
}

// ---------------------------------------------------------------------------
// head: exact fp64 GEMM2 + LIF2 + pooling.
// ---------------------------------------------------------------------------
__global__ __launch_bounds__(320) void head_kernel(const float* __restrict__ S,
                                                   const float* __restrict__ W2,
                                                   const float* __restrict__ b2,
                                                   float* __restrict__ out) {
  __shared__ float w2s[N1 * NC];
  __shared__ float srow[N1];
  __shared__ double part[320];
  __shared__ double red[NC];

  const int tid = threadIdx.x;
  const int b = blockIdx.x;

  for (int i = tid; i < N1 * NC; i += 320) w2s[i] = W2[i];

  const int q  = tid / NC;
  const int c  = tid % NC;
  const int h0 = q * 64;

  double mem = 0.0, spk = 0.0, ssum = 0.0;
  const double bias = (double)b2[c];

  for (int t = 0; t < TT; ++t) {
    const float* sp = S + ((size_t)(b * TT + t)) * N1;
    for (int i = tid; i < N1; i += 320) srow[i] = sp[i];
    __syncthreads();

    double p = 0.0;
#pragma unroll 16
    for (int h = 0; h < 64; ++h)
      p += (double)srow[h0 + h] * (double)w2s[(h0 + h) * NC + c];
    part[tid] = p;
    __syncthreads();

    if (tid < NC) {
      double y = bias;
#pragma unroll
      for (int qq = 0; qq < 8; ++qq) y += part[tid + qq * NC];
      mem = mem * 0.5 * (1.0 - spk) + y;
      spk = (mem > 1.0) ? 1.0 : 0.0;
      ssum += spk;
    }
    __syncthreads();
  }

  if (tid < NC) red[tid] = ssum;
  __syncthreads();
  if (tid < 4) {
    double s = 0.0;
#pragma unroll
    for (int i = 0; i < 10; ++i) s += red[tid * 10 + i];
    out[b * 4 + tid] = (float)(s * (1.0 / 640.0));
  }
}

extern "C" void kernel_launch(void* const* d_in, const int* in_sizes, int n_in,
                              void* d_out, int out_size, void* d_ws, size_t ws_size,
                              hipStream_t stream) {
  const float* x  = (const float*)d_in[0];
  const float* W1 = (const float*)d_in[1];
  const float* b1 = (const float*)d_in[2];
  const float* W2 = (const float*)d_in[3];
  const float* b2 = (const float*)d_in[4];
  float* out = (float*)d_out;

  char* ws = (char*)d_ws;
  float*    Sb    = (float*)(ws + S_OFF);
  __bf16*   W1hi  = (__bf16*)(ws + W1HI_OFF);
  __bf16*   W1mid = (__bf16*)(ws + W1MID_OFF);
  float*    W1T   = (float*)(ws + W1T_OFF);
  unsigned* cnt   = (unsigned*)(ws + CNT_OFF);
  unsigned* list  = (unsigned*)(ws + LIST_OFF);

  hipMemsetAsync(cnt, 0, 4, stream);
  prep<<<dim3(64, 8), dim3(256), 0, stream>>>(W1, W1hi, W1mid, W1T);
  gemm_fast<<<dim3(8, 128), dim3(256), 0, stream>>>(x, W1hi, W1mid, b1, Sb, cnt, list);
  fixup<<<dim3(512), dim3(256), 0, stream>>>(x, W1T, b1, cnt, list, Sb);
  head_kernel<<<dim3(256), dim3(320), 0, stream>>>(Sb, W2, b2, out);
}

// Round 7
// 482.901 us; speedup vs baseline: 5.8153x; 1.0894x over previous
//
#include <hip/hip_runtime.h>

typedef __bf16 bf16x8 __attribute__((ext_vector_type(8)));
typedef float f32x16 __attribute__((ext_vector_type(16)));

constexpr int K1 = 4096;
constexpr int N1 = 512;
constexpr int TT = 64;
constexpr int NC = 40;
constexpr float EPS = 2e-4f;   // flag threshold on |mem-1|; fast-path err ~5e-6 rms
constexpr unsigned CAP = 32768;

// ws layout (bytes)
constexpr size_t S_OFF    = 0;                       // 16384*512 f32
constexpr size_t W1T_OFF  = 33554432;                // [512][4096] f32 (fixup)
constexpr size_t PKH_OFF  = 41943040;                // packed B-frag hi, 4 MB
constexpr size_t PKM_OFF  = 46137344;                // packed B-frag mid, 4 MB
constexpr size_t CNT_OFF  = 50331648;
constexpr size_t LIST_OFF = 50331904;

union U8 { ushort u[8]; uint4 v; };
union BC { __bf16 b; ushort s; };

// ---------------------------------------------------------------------------
// prep_t: W1 [4096][512] -> W1T [512][4096] f32 (exact, for fixup).
// ---------------------------------------------------------------------------
__global__ __launch_bounds__(256) void prep_t(const float* __restrict__ W1,
                                              float* __restrict__ W1T) {
  __shared__ float tile[64][65];
  const int kb = blockIdx.x * 64;
  const int nb = blockIdx.y * 64;
  const int r  = threadIdx.x >> 2;
  const int c0 = (threadIdx.x & 3) * 16;
  const float4* src = (const float4*)(W1 + (size_t)(kb + r) * N1 + nb + c0);
#pragma unroll
  for (int u = 0; u < 4; ++u) {
    float4 v = src[u];
    tile[r][c0 + u * 4 + 0] = v.x;
    tile[r][c0 + u * 4 + 1] = v.y;
    tile[r][c0 + u * 4 + 2] = v.z;
    tile[r][c0 + u * 4 + 3] = v.w;
  }
  __syncthreads();
  const size_t ob = (size_t)(nb + r) * K1 + kb + c0;
#pragma unroll
  for (int u = 0; u < 4; ++u) {
    float4 o = make_float4(tile[c0 + u * 4 + 0][r], tile[c0 + u * 4 + 1][r],
                           tile[c0 + u * 4 + 2][r], tile[c0 + u * 4 + 3][r]);
    *(float4*)(W1T + ob + u * 4) = o;
  }
}

// ---------------------------------------------------------------------------
// prep_pack: W1 -> MFMA B-fragment-ordered hi/mid bf16 packs.
// Frag f = s*256 + kc (s = n/32, kc = k/16). Entry [f][lane] = 8 bf16:
// elem j = W1[k = kc*16 + 8*(lane>>5) + j][n = s*32 + (lane&31)].
// gemm then reads a whole B fragment as one coalesced 16B/lane load.
// ---------------------------------------------------------------------------
__global__ __launch_bounds__(256) void prep_pack(const float* __restrict__ W1,
                                                 uint4* __restrict__ pkh,
                                                 uint4* __restrict__ pkm) {
  const int tid = threadIdx.x;
  const int lane = tid & 63;
  const int f = blockIdx.x * 4 + (tid >> 6);
  const int s = f >> 8, kc = f & 255;
  const int n = s * 32 + (lane & 31);
  const int kbase = kc * 16 + (lane >> 5) * 8;
  U8 hh, mm;
#pragma unroll
  for (int j = 0; j < 8; ++j) {
    const float v = W1[(size_t)(kbase + j) * N1 + n];
    __bf16 h = (__bf16)v;
    __bf16 m = (__bf16)(v - (float)h);
    BC ch; ch.b = h; BC cm; cm.b = m;
    hh.u[j] = ch.s;
    mm.u[j] = cm.s;
  }
  pkh[(size_t)f * 64 + lane] = hh.v;
  pkm[(size_t)f * 64 + lane] = mm.v;
}

// ---------------------------------------------------------------------------
// gemm_fast: 3-term bf16-split via 32x32x16 MFMA, fused fp32 LIF1 + flagging.
// Block 128M x 128N, BK=32, 4 waves (2M x 2N), wave tile 64x64 (mt=2, nt=2).
// A through padded LDS (80B rows, conflict-minimal); B fragments loaded
// directly from the global packs (coalesced, L2/L3-resident), prefetched one
// K-step ahead. Grid 512 blocks, XCD m-stripe swizzle.
// ---------------------------------------------------------------------------
__global__ __launch_bounds__(256, 2) void gemm_fast(const float* __restrict__ x,
                                                    const uint4* __restrict__ pkh,
                                                    const uint4* __restrict__ pkm,
                                                    const float* __restrict__ b1,
                                                    float* __restrict__ S,
                                                    unsigned* __restrict__ cnt,
                                                    unsigned* __restrict__ list) {
  __shared__ __attribute__((aligned(16))) char lds[32768];
  char* const Ahi  = lds;            // [128][32] bf16, 80B rows = 10240
  char* const Amid = lds + 10240;
  float* const dS  = (float*)lds;    // [64 t][128 n] f32, epilogue alias (32KB)

  const int tid = threadIdx.x;
  const int lane = tid & 63, wid = tid >> 6;
  const int lr = lane & 31, lhi = lane >> 5;
  const int wm = (wid & 1) * 64;     // m-half
  const int wq = wid >> 1;           // n-quarter (0/1) -> wn = wq*64

  // XCD m-stripe swizzle: 8 XCDs x 16 m-blocks; n fastest within stripe.
  const int id = blockIdx.x;
  const int xcd = id & 7, sq = id >> 3;
  const int m_blk = xcd * 16 + (sq >> 2);
  const int n_blk = sq & 3;
  const int bm = m_blk * 128, bn = n_blk * 128;

  // A staging map: thread -> row 0..127, k-half 0/16
  const int ar = tid >> 1, ak = (tid & 1) * 16;
  const float* Ap = x + (size_t)(bm + ar) * K1 + ak;
  const int aoff = ar * 80 + ak * 2;

  // B fragment indices: s = n_blk*4 + wq*2 + nt; frag f = s*256 + kc
  const int s0 = n_blk * 4 + wq * 2;

  f32x16 acc[2][2] = {};
  float4 av[4];
  uint4 bh[2][2], bm_[2][2];   // [kh][nt] current K-step's B frags

#pragma unroll
  for (int u = 0; u < 4; ++u) av[u] = *(const float4*)(Ap + u * 4);
#pragma unroll
  for (int kh = 0; kh < 2; ++kh)
#pragma unroll
    for (int nt = 0; nt < 2; ++nt) {
      const size_t fi = ((size_t)((s0 + nt) * 256 + kh)) * 64 + lane;
      bh[kh][nt] = pkh[fi];
      bm_[kh][nt] = pkm[fi];
    }

  for (int k0 = 0; k0 < K1; k0 += 32) {
    __syncthreads();
    // split A fp32 -> hi/mid bf16 and stage
    U8 hA[2], mA[2];
#pragma unroll
    for (int u = 0; u < 4; ++u) {
      float ff[4] = {av[u].x, av[u].y, av[u].z, av[u].w};
#pragma unroll
      for (int j = 0; j < 4; ++j) {
        int idx = u * 4 + j;
        float f = ff[j];
        __bf16 h = (__bf16)f;
        __bf16 m = (__bf16)(f - (float)h);
        BC ch; ch.b = h; BC cm; cm.b = m;
        hA[idx >> 3].u[idx & 7] = ch.s;
        mA[idx >> 3].u[idx & 7] = cm.s;
      }
    }
    *(uint4*)(Ahi + aoff)       = hA[0].v;
    *(uint4*)(Ahi + aoff + 16)  = hA[1].v;
    *(uint4*)(Amid + aoff)      = mA[0].v;
    *(uint4*)(Amid + aoff + 16) = mA[1].v;
    __syncthreads();

    // prefetch next K-step (x slice + B frags)
    uint4 nbh[2][2], nbm[2][2];
    if (k0 + 32 < K1) {
#pragma unroll
      for (int u = 0; u < 4; ++u) av[u] = *(const float4*)(Ap + k0 + 32 + u * 4);
      const int kc = (k0 >> 4) + 2;
#pragma unroll
      for (int kh = 0; kh < 2; ++kh)
#pragma unroll
        for (int nt = 0; nt < 2; ++nt) {
          const size_t fi = ((size_t)((s0 + nt) * 256 + kc + kh)) * 64 + lane;
          nbh[kh][nt] = pkh[fi];
          nbm[kh][nt] = pkm[fi];
        }
    }

    // MFMA: per kh, per mt: read A frags once, 3 terms vs both nt
#pragma unroll
    for (int kh = 0; kh < 2; ++kh) {
      const int fo = kh * 32 + lhi * 16;
#pragma unroll
      for (int mt = 0; mt < 2; ++mt) {
        const int ao = (wm + mt * 32 + lr) * 80 + fo;
        bf16x8 ah = *(const bf16x8*)(Ahi + ao);
        bf16x8 am = *(const bf16x8*)(Amid + ao);
#pragma unroll
        for (int nt = 0; nt < 2; ++nt) {
          const bf16x8 vbh = __builtin_bit_cast(bf16x8, bh[kh][nt]);
          const bf16x8 vbm = __builtin_bit_cast(bf16x8, bm_[kh][nt]);
          acc[mt][nt] = __builtin_amdgcn_mfma_f32_32x32x16_bf16(am, vbh, acc[mt][nt], 0, 0, 0);
          acc[mt][nt] = __builtin_amdgcn_mfma_f32_32x32x16_bf16(ah, vbm, acc[mt][nt], 0, 0, 0);
          acc[mt][nt] = __builtin_amdgcn_mfma_f32_32x32x16_bf16(ah, vbh, acc[mt][nt], 0, 0, 0);
        }
      }
    }

    if (k0 + 32 < K1) {
#pragma unroll
      for (int kh = 0; kh < 2; ++kh)
#pragma unroll
        for (int nt = 0; nt < 2; ++nt) {
          bh[kh][nt] = nbh[kh][nt];
          bm_[kh][nt] = nbm[kh][nt];
        }
    }
  }

  // Epilogue: per 64-row half (one batch), stage y f32, fp32 LIF1 + flagging.
#pragma unroll
  for (int half = 0; half < 2; ++half) {
    __syncthreads();
    if ((wid & 1) == half) {
#pragma unroll
      for (int mt = 0; mt < 2; ++mt)
#pragma unroll
        for (int nt = 0; nt < 2; ++nt)
#pragma unroll
          for (int r = 0; r < 16; ++r) {
            const int row = mt * 32 + (r & 3) + 8 * (r >> 2) + 4 * lhi;
            const int col = wq * 64 + nt * 32 + lr;
            dS[row * 128 + col] = acc[mt][nt][r];
          }
    }
    __syncthreads();
    if (tid < 128) {
      const int n = tid;
      const int b = m_blk * 2 + half;
      const float bias = b1[bn + n];
      float mem = 0.0f, spk = 0.0f, mn = 1e9f;
      for (int t = 0; t < TT; ++t) {
        const float y = dS[t * 128 + n] + bias;
        mem = mem * 0.5f * (1.0f - spk) + y;
        const float d = mem - 1.0f;
        mn = fminf(mn, fabsf(d));
        spk = (d > 0.0f) ? 1.0f : 0.0f;
        S[((size_t)(b * TT + t)) * N1 + bn + n] = spk;
      }
      if (mn < EPS) {
        unsigned idx = atomicAdd(cnt, 1u);
        if (idx < CAP) list[idx] = ((unsigned)b << 16) | (unsigned)(bn + n);
      }
    }
  }
}

// ---------------------------------------------------------------------------
// fixup: grid-stride over flagged entries; one block per entry; coalesced
// fp64 recompute of the full trajectory, overwrites S.
// ---------------------------------------------------------------------------
__global__ __launch_bounds__(256) void fixup(const float* __restrict__ x,
                                             const float* __restrict__ W1T,
                                             const float* __restrict__ b1,
                                             const unsigned* __restrict__ cnt,
                                             const unsigned* __restrict__ list,
                                             float* __restrict__ S) {
  __shared__ double yrow[TT];
  const int tid = threadIdx.x;
  const int lane = tid & 63, w = tid >> 6;
  const int count = (int)min(*cnt, CAP);

  for (int e = blockIdx.x; e < count; e += gridDim.x) {
    const unsigned ent = list[e];
    const int b = (int)(ent >> 16), n = (int)(ent & 0xffffu);
    const float4* wr = (const float4*)(W1T + (size_t)n * K1);
#pragma unroll 1
    for (int i = 0; i < 16; ++i) {
      const int t = w * 16 + i;
      const float4* xr = (const float4*)(x + ((size_t)(b * TT + t)) * K1);
      double p = 0.0;
#pragma unroll
      for (int j = 0; j < 16; ++j) {
        const float4 xv = xr[lane + 64 * j];
        const float4 wv = wr[lane + 64 * j];
        p += (double)xv.x * (double)wv.x + (double)xv.y * (double)wv.y +
             (double)xv.z * (double)wv.z + (double)xv.w * (double)wv.w;
      }
#pragma unroll
      for (int off = 1; off < 64; off <<= 1) p += __shfl_xor(p, off);
      if (lane == 0) yrow[t] = p;
    }
    __syncthreads();
    if (tid == 0) {
      double mem = 0.0, spk = 0.0;
      const double bias = (double)b1[n];
      for (int t2 = 0; t2 < TT; ++t2) {
        const double y = yrow[t2] + bias;
        mem = mem * 0.5 * (1.0 - spk) + y;
        spk = (mem > 1.0) ? 1.0 : 0.0;
        S[((size_t)(b * TT + t2)) * N1 + n] = (float)spk;
      }
    }
    __syncthreads();
  }
}

// ---------------------------------------------------------------------------
// head: exact fp64 GEMM2 + LIF2 + pooling.
// ---------------------------------------------------------------------------
__global__ __launch_bounds__(320) void head_kernel(const float* __restrict__ S,
                                                   const float* __restrict__ W2,
                                                   const float* __restrict__ b2,
                                                   float* __restrict__ out) {
  __shared__ float w2s[N1 * NC];
  __shared__ float srow[N1];
  __shared__ double part[320];
  __shared__ double red[NC];

  const int tid = threadIdx.x;
  const int b = blockIdx.x;

  for (int i = tid; i < N1 * NC; i += 320) w2s[i] = W2[i];

  const int q  = tid / NC;
  const int c  = tid % NC;
  const int h0 = q * 64;

  double mem = 0.0, spk = 0.0, ssum = 0.0;
  const double bias = (double)b2[c];

  for (int t = 0; t < TT; ++t) {
    const float* sp = S + ((size_t)(b * TT + t)) * N1;
    for (int i = tid; i < N1; i += 320) srow[i] = sp[i];
    __syncthreads();

    double p = 0.0;
#pragma unroll 16
    for (int h = 0; h < 64; ++h)
      p += (double)srow[h0 + h] * (double)w2s[(h0 + h) * NC + c];
    part[tid] = p;
    __syncthreads();

    if (tid < NC) {
      double y = bias;
#pragma unroll
      for (int qq = 0; qq < 8; ++qq) y += part[tid + qq * NC];
      mem = mem * 0.5 * (1.0 - spk) + y;
      spk = (mem > 1.0) ? 1.0 : 0.0;
      ssum += spk;
    }
    __syncthreads();
  }

  if (tid < NC) red[tid] = ssum;
  __syncthreads();
  if (tid < 4) {
    double s = 0.0;
#pragma unroll
    for (int i = 0; i < 10; ++i) s += red[tid * 10 + i];
    out[b * 4 + tid] = (float)(s * (1.0 / 640.0));
  }
}

extern "C" void kernel_launch(void* const* d_in, const int* in_sizes, int n_in,
                              void* d_out, int out_size, void* d_ws, size_t ws_size,
                              hipStream_t stream) {
  const float* x  = (const float*)d_in[0];
  const float* W1 = (const float*)d_in[1];
  const float* b1 = (const float*)d_in[2];
  const float* W2 = (const float*)d_in[3];
  const float* b2 = (const float*)d_in[4];
  float* out = (float*)d_out;

  char* ws = (char*)d_ws;
  float*    Sb   = (float*)(ws + S_OFF);
  float*    W1T  = (float*)(ws + W1T_OFF);
  uint4*    pkh  = (uint4*)(ws + PKH_OFF);
  uint4*    pkm  = (uint4*)(ws + PKM_OFF);
  unsigned* cnt  = (unsigned*)(ws + CNT_OFF);
  unsigned* list = (unsigned*)(ws + LIST_OFF);

  hipMemsetAsync(cnt, 0, 4, stream);
  prep_t<<<dim3(64, 8), dim3(256), 0, stream>>>(W1, W1T);
  prep_pack<<<dim3(1024), dim3(256), 0, stream>>>(W1, pkh, pkm);
  gemm_fast<<<dim3(512), dim3(256), 0, stream>>>(x, pkh, pkm, b1, Sb, cnt, list);
  fixup<<<dim3(512), dim3(256), 0, stream>>>(x, W1T, b1, cnt, list, Sb);
  head_kernel<<<dim3(256), dim3(320), 0, stream>>>(Sb, W2, b2, out);
}

// Round 8
// 475.958 us; speedup vs baseline: 5.9001x; 1.0146x over previous
//
#include <hip/hip_runtime.h>

typedef __bf16 bf16x8 __attribute__((ext_vector_type(8)));
typedef float f32x16 __attribute__((ext_vector_type(16)));

constexpr int K1 = 4096;
constexpr int N1 = 512;
constexpr int TT = 64;
constexpr int NC = 40;
constexpr float EPS = 2e-4f;   // flag threshold; fast-path err sigma ~2.5e-5
constexpr unsigned CAP = 32768;

// ws layout (bytes)
constexpr size_t S_OFF    = 0;                       // 16384*512 f32
constexpr size_t W1T_OFF  = 33554432;                // [512][4096] f32 (fixup)
constexpr size_t PKH_OFF  = 41943040;                // packed B-frag hi, 4 MB
constexpr size_t PKM_OFF  = 46137344;                // packed B-frag mid, 4 MB
constexpr size_t CNT_OFF  = 50331648;
constexpr size_t LIST_OFF = 50331904;

// split a pair of f32 into packed bf16 hi (u32) + packed bf16 mid (u32), RNE
__device__ __forceinline__ void split_pair(float f0, float f1,
                                           unsigned& hp, unsigned& mp) {
  asm("v_cvt_pk_bf16_f32 %0, %1, %2" : "=v"(hp) : "v"(f0), "v"(f1));
  unsigned h0b = hp << 16;
  unsigned h1b = hp & 0xFFFF0000u;
  float m0 = f0 - __builtin_bit_cast(float, h0b);
  float m1 = f1 - __builtin_bit_cast(float, h1b);
  asm("v_cvt_pk_bf16_f32 %0, %1, %2" : "=v"(mp) : "v"(m0), "v"(m1));
}

// ---------------------------------------------------------------------------
// prep: per 64k x 64n tile of W1: write W1T (f32 [n][k], for fixup) and the
// MFMA B-fragment-ordered bf16 hi/mid packs.
// Pack entry [f][lane], f = s*256 + kc: elem j = W1[kc*16 + 8*(lane>>5) + j]
// [s*32 + (lane&31)].
// ---------------------------------------------------------------------------
__global__ __launch_bounds__(256) void prep(const float* __restrict__ W1,
                                            float* __restrict__ W1T,
                                            uint4* __restrict__ pkh,
                                            uint4* __restrict__ pkm) {
  __shared__ float tile[64][65];
  const int tid = threadIdx.x;
  const int kb = blockIdx.x * 64;
  const int nb = blockIdx.y * 64;
  const int r  = tid >> 2;
  const int c0 = (tid & 3) * 16;
  const float4* src = (const float4*)(W1 + (size_t)(kb + r) * N1 + nb + c0);
#pragma unroll
  for (int u = 0; u < 4; ++u) {
    float4 v = src[u];
    tile[r][c0 + u * 4 + 0] = v.x;
    tile[r][c0 + u * 4 + 1] = v.y;
    tile[r][c0 + u * 4 + 2] = v.z;
    tile[r][c0 + u * 4 + 3] = v.w;
  }
  __syncthreads();
  // W1T: row n = nb + r, k = kb + c0 .. +15
  const size_t ob = (size_t)(nb + r) * K1 + kb + c0;
#pragma unroll
  for (int u = 0; u < 4; ++u) {
    float4 o = make_float4(tile[c0 + u * 4 + 0][r], tile[c0 + u * 4 + 1][r],
                           tile[c0 + u * 4 + 2][r], tile[c0 + u * 4 + 3][r]);
    *(float4*)(W1T + ob + u * 4) = o;
  }
  // pack: 512 slots (8 frags x 64 lanes), 2 per thread
#pragma unroll
  for (int sl = 0; sl < 2; ++sl) {
    const int slot = tid + sl * 256;
    const int frag_loc = slot >> 6, lane = slot & 63;
    const int kc_loc = frag_loc >> 1, s_loc = frag_loc & 1;
    const int n_loc = s_loc * 32 + (lane & 31);
    const int k_base = kc_loc * 16 + (lane >> 5) * 8;
    uint4 hh, mm;
    unsigned* hw = (unsigned*)&hh;
    unsigned* mw = (unsigned*)&mm;
#pragma unroll
    for (int p = 0; p < 4; ++p)
      split_pair(tile[k_base + 2 * p][n_loc], tile[k_base + 2 * p + 1][n_loc],
                 hw[p], mw[p]);
    const size_t f = (size_t)((nb >> 5) + s_loc) * 256 + (kb >> 4) + kc_loc;
    pkh[f * 64 + lane] = hh;
    pkm[f * 64 + lane] = mm;
  }
}

// ---------------------------------------------------------------------------
// gemm_fast: 3-term bf16-split via 32x32x16 MFMA, fused fp32 LIF1 + flagging.
// Block 128M x 128N, 4 waves (2M x 2N), wave tile 64x64. BK=32.
// A: fp32 global (coalesced) -> cvt_pk split -> frag-order LDS, DOUBLE-
// buffered, ONE barrier per K-step. B: direct global->reg from pack,
// ping-pong one step ahead. Grid 512, XCD m-stripe swizzle.
// ---------------------------------------------------------------------------
__global__ __launch_bounds__(256, 2) void gemm_fast(const float* __restrict__ x,
                                                    const uint4* __restrict__ pkh,
                                                    const uint4* __restrict__ pkm,
                                                    const float* __restrict__ b1,
                                                    float* __restrict__ S,
                                                    unsigned* __restrict__ cnt,
                                                    unsigned* __restrict__ list) {
  __shared__ __attribute__((aligned(16))) char lds[32768];
  // buf b at lds + b*16384: hi [2kh][4 m32][64 lane][16B] = 8KB, mid at +8192
  float* const dS = (float*)lds;     // [64 t][128 n] f32 epilogue alias

  const int tid = threadIdx.x;
  const int lane = tid & 63, wid = tid >> 6;
  const int lr = lane & 31;
  const int wm = (wid & 1) * 64;     // m-half
  const int wq = wid >> 1;           // n-half

  const int id = blockIdx.x;
  const int xcd = id & 7, sq = id >> 3;
  const int m_blk = xcd * 16 + (sq >> 2);
  const int n_blk = sq & 3;
  const int bm = m_blk * 128, bn = n_blk * 128;

  // A staging map: thread -> (row, k-half16)
  const int ar = tid >> 1, akh = tid & 1;
  const float* Ap = x + (size_t)(bm + ar) * K1 + akh * 16;
  const int wr0 = (akh * 4 + (ar >> 5)) * 1024 + (ar & 31) * 16;

  // B frag base pointers: s = n_blk*4 + wq*2 + nt
  const int s0 = n_blk * 4 + wq * 2;
  const uint4* pbh[2][2];
  const uint4* pbm[2][2];
#pragma unroll
  for (int kh = 0; kh < 2; ++kh)
#pragma unroll
    for (int nt = 0; nt < 2; ++nt) {
      const size_t base = ((size_t)(s0 + nt) * 256 + kh) * 64 + lane;
      pbh[kh][nt] = pkh + base;
      pbm[kh][nt] = pkm + base;
    }
  // at K-offset k0, frag kc index = k0>>4 -> pointer offset (k0>>4)*64 = k0*4

  f32x16 acc[2][2] = {};
  float4 av[4];
  uint4 bch[2][2], bcm[2][2], bnh[2][2], bnm[2][2];

#pragma unroll
  for (int u = 0; u < 4; ++u) av[u] = *(const float4*)(Ap + u * 4);
#pragma unroll
  for (int kh = 0; kh < 2; ++kh)
#pragma unroll
    for (int nt = 0; nt < 2; ++nt) {
      bch[kh][nt] = pbh[kh][nt][0];
      bcm[kh][nt] = pbm[kh][nt][0];
      bnh[kh][nt] = pbh[kh][nt][32 * 4];
      bnm[kh][nt] = pbm[kh][nt][32 * 4];
    }

  // prologue: split slice 0 into buf0, prefetch slice 1
  {
    uint4 hi[2], mi[2];
    unsigned* hw = (unsigned*)hi;
    unsigned* mw = (unsigned*)mi;
#pragma unroll
    for (int u = 0; u < 4; ++u) {
      split_pair(av[u].x, av[u].y, hw[2 * u], mw[2 * u]);
      split_pair(av[u].z, av[u].w, hw[2 * u + 1], mw[2 * u + 1]);
    }
    *(uint4*)(lds + wr0)              = hi[0];
    *(uint4*)(lds + wr0 + 512)        = hi[1];
    *(uint4*)(lds + 8192 + wr0)       = mi[0];
    *(uint4*)(lds + 8192 + wr0 + 512) = mi[1];
#pragma unroll
    for (int u = 0; u < 4; ++u) av[u] = *(const float4*)(Ap + 32 + u * 4);
  }

  for (int k0 = 0; k0 < K1; k0 += 32) {
    const int cur = (k0 >> 5) & 1;
    char* const bufc = lds + cur * 16384;
    char* const bufn = lds + (cur ^ 1) * 16384;
    __syncthreads();

    if (k0 + 32 < K1) {
      uint4 hi[2], mi[2];
      unsigned* hw = (unsigned*)hi;
      unsigned* mw = (unsigned*)mi;
#pragma unroll
      for (int u = 0; u < 4; ++u) {
        split_pair(av[u].x, av[u].y, hw[2 * u], mw[2 * u]);
        split_pair(av[u].z, av[u].w, hw[2 * u + 1], mw[2 * u + 1]);
      }
      *(uint4*)(bufn + wr0)              = hi[0];
      *(uint4*)(bufn + wr0 + 512)        = hi[1];
      *(uint4*)(bufn + 8192 + wr0)       = mi[0];
      *(uint4*)(bufn + 8192 + wr0 + 512) = mi[1];
    }
    if (k0 + 64 < K1) {
#pragma unroll
      for (int u = 0; u < 4; ++u) av[u] = *(const float4*)(Ap + k0 + 64 + u * 4);
    }

    // MFMA on buf[cur] with bc
#pragma unroll
    for (int kh = 0; kh < 2; ++kh) {
#pragma unroll
      for (int mt = 0; mt < 2; ++mt) {
        const int region = (kh * 4 + (wm >> 5) + mt) * 1024 + lane * 16;
        bf16x8 ah = *(const bf16x8*)(bufc + region);
        bf16x8 am = *(const bf16x8*)(bufc + 8192 + region);
#pragma unroll
        for (int nt = 0; nt < 2; ++nt) {
          const bf16x8 vbh = __builtin_bit_cast(bf16x8, bch[kh][nt]);
          const bf16x8 vbm = __builtin_bit_cast(bf16x8, bcm[kh][nt]);
          acc[mt][nt] = __builtin_amdgcn_mfma_f32_32x32x16_bf16(am, vbh, acc[mt][nt], 0, 0, 0);
          acc[mt][nt] = __builtin_amdgcn_mfma_f32_32x32x16_bf16(ah, vbm, acc[mt][nt], 0, 0, 0);
          acc[mt][nt] = __builtin_amdgcn_mfma_f32_32x32x16_bf16(ah, vbh, acc[mt][nt], 0, 0, 0);
        }
      }
    }

    // rotate B, prefetch next
#pragma unroll
    for (int kh = 0; kh < 2; ++kh)
#pragma unroll
      for (int nt = 0; nt < 2; ++nt) {
        bch[kh][nt] = bnh[kh][nt];
        bcm[kh][nt] = bnm[kh][nt];
      }
    if (k0 + 64 < K1) {
      const int off = (k0 + 64) * 4;
#pragma unroll
      for (int kh = 0; kh < 2; ++kh)
#pragma unroll
        for (int nt = 0; nt < 2; ++nt) {
          bnh[kh][nt] = pbh[kh][nt][off];
          bnm[kh][nt] = pbm[kh][nt][off];
        }
    }
  }

  // Epilogue: per 64-row half (one batch), stage y f32, fp32 LIF1 + flagging.
#pragma unroll
  for (int half = 0; half < 2; ++half) {
    __syncthreads();
    if ((wid & 1) == half) {
      const int lhi = lane >> 5;
#pragma unroll
      for (int mt = 0; mt < 2; ++mt)
#pragma unroll
        for (int nt = 0; nt < 2; ++nt)
#pragma unroll
          for (int r = 0; r < 16; ++r) {
            const int row = mt * 32 + (r & 3) + 8 * (r >> 2) + 4 * lhi;
            const int col = wq * 64 + nt * 32 + lr;
            dS[row * 128 + col] = acc[mt][nt][r];
          }
    }
    __syncthreads();
    if (tid < 128) {
      const int n = tid;
      const int b = m_blk * 2 + half;
      const float bias = b1[bn + n];
      float mem = 0.0f, spk = 0.0f, mn = 1e9f;
      for (int t = 0; t < TT; ++t) {
        const float y = dS[t * 128 + n] + bias;
        mem = mem * 0.5f * (1.0f - spk) + y;
        const float d = mem - 1.0f;
        mn = fminf(mn, fabsf(d));
        spk = (d > 0.0f) ? 1.0f : 0.0f;
        S[((size_t)(b * TT + t)) * N1 + bn + n] = spk;
      }
      if (mn < EPS) {
        unsigned idx = atomicAdd(cnt, 1u);
        if (idx < CAP) list[idx] = ((unsigned)b << 16) | (unsigned)(bn + n);
      }
    }
  }
}

// ---------------------------------------------------------------------------
// fixup: grid-stride over flagged entries; one block per entry; coalesced
// fp64 recompute of the full trajectory, overwrites S.
// ---------------------------------------------------------------------------
__global__ __launch_bounds__(256) void fixup(const float* __restrict__ x,
                                             const float* __restrict__ W1T,
                                             const float* __restrict__ b1,
                                             const unsigned* __restrict__ cnt,
                                             const unsigned* __restrict__ list,
                                             float* __restrict__ S) {
  __shared__ double yrow[TT];
  const int tid = threadIdx.x;
  const int lane = tid & 63, w = tid >> 6;
  const int count = (int)min(*cnt, CAP);

  for (int e = blockIdx.x; e < count; e += gridDim.x) {
    const unsigned ent = list[e];
    const int b = (int)(ent >> 16), n = (int)(ent & 0xffffu);
    const float4* wr = (const float4*)(W1T + (size_t)n * K1);
#pragma unroll 1
    for (int i = 0; i < 16; ++i) {
      const int t = w * 16 + i;
      const float4* xr = (const float4*)(x + ((size_t)(b * TT + t)) * K1);
      double p = 0.0;
#pragma unroll
      for (int j = 0; j < 16; ++j) {
        const float4 xv = xr[lane + 64 * j];
        const float4 wv = wr[lane + 64 * j];
        p += (double)xv.x * (double)wv.x + (double)xv.y * (double)wv.y +
             (double)xv.z * (double)wv.z + (double)xv.w * (double)wv.w;
      }
#pragma unroll
      for (int off = 1; off < 64; off <<= 1) p += __shfl_xor(p, off);
      if (lane == 0) yrow[t] = p;
    }
    __syncthreads();
    if (tid == 0) {
      double mem = 0.0, spk = 0.0;
      const double bias = (double)b1[n];
      for (int t2 = 0; t2 < TT; ++t2) {
        const double y = yrow[t2] + bias;
        mem = mem * 0.5 * (1.0 - spk) + y;
        spk = (mem > 1.0) ? 1.0 : 0.0;
        S[((size_t)(b * TT + t2)) * N1 + n] = (float)spk;
      }
    }
    __syncthreads();
  }
}

// ---------------------------------------------------------------------------
// head: exact fp64 GEMM2 + LIF2 + pooling.
// ---------------------------------------------------------------------------
__global__ __launch_bounds__(320) void head_kernel(const float* __restrict__ S,
                                                   const float* __restrict__ W2,
                                                   const float* __restrict__ b2,
                                                   float* __restrict__ out) {
  __shared__ float w2s[N1 * NC];
  __shared__ float srow[N1];
  __shared__ double part[320];
  __shared__ double red[NC];

  const int tid = threadIdx.x;
  const int b = blockIdx.x;

  for (int i = tid; i < N1 * NC; i += 320) w2s[i] = W2[i];

  const int q  = tid / NC;
  const int c  = tid % NC;
  const int h0 = q * 64;

  double mem = 0.0, spk = 0.0, ssum = 0.0;
  const double bias = (double)b2[c];

  for (int t = 0; t < TT; ++t) {
    const float* sp = S + ((size_t)(b * TT + t)) * N1;
    for (int i = tid; i < N1; i += 320) srow[i] = sp[i];
    __syncthreads();

    double p = 0.0;
#pragma unroll 16
    for (int h = 0; h < 64; ++h)
      p += (double)srow[h0 + h] * (double)w2s[(h0 + h) * NC + c];
    part[tid] = p;
    __syncthreads();

    if (tid < NC) {
      double y = bias;
#pragma unroll
      for (int qq = 0; qq < 8; ++qq) y += part[tid + qq * NC];
      mem = mem * 0.5 * (1.0 - spk) + y;
      spk = (mem > 1.0) ? 1.0 : 0.0;
      ssum += spk;
    }
    __syncthreads();
  }

  if (tid < NC) red[tid] = ssum;
  __syncthreads();
  if (tid < 4) {
    double s = 0.0;
#pragma unroll
    for (int i = 0; i < 10; ++i) s += red[tid * 10 + i];
    out[b * 4 + tid] = (float)(s * (1.0 / 640.0));
  }
}

extern "C" void kernel_launch(void* const* d_in, const int* in_sizes, int n_in,
                              void* d_out, int out_size, void* d_ws, size_t ws_size,
                              hipStream_t stream) {
  const float* x  = (const float*)d_in[0];
  const float* W1 = (const float*)d_in[1];
  const float* b1 = (const float*)d_in[2];
  const float* W2 = (const float*)d_in[3];
  const float* b2 = (const float*)d_in[4];
  float* out = (float*)d_out;

  char* ws = (char*)d_ws;
  float*    Sb   = (float*)(ws + S_OFF);
  float*    W1T  = (float*)(ws + W1T_OFF);
  uint4*    pkh  = (uint4*)(ws + PKH_OFF);
  uint4*    pkm  = (uint4*)(ws + PKM_OFF);
  unsigned* cnt  = (unsigned*)(ws + CNT_OFF);
  unsigned* list = (unsigned*)(ws + LIST_OFF);

  hipMemsetAsync(cnt, 0, 4, stream);
  prep<<<dim3(64, 8), dim3(256), 0, stream>>>(W1, W1T, pkh, pkm);
  gemm_fast<<<dim3(512), dim3(256), 0, stream>>>(x, pkh, pkm, b1, Sb, cnt, list);
  fixup<<<dim3(512), dim3(256), 0, stream>>>(x, W1T, b1, cnt, list, Sb);
  head_kernel<<<dim3(256), dim3(320), 0, stream>>>(Sb, W2, b2, out);
}

// Round 9
// 348.750 us; speedup vs baseline: 8.0522x; 1.3648x over previous
//
#include <hip/hip_runtime.h>

typedef __bf16 bf16x8 __attribute__((ext_vector_type(8)));
typedef float f32x16 __attribute__((ext_vector_type(16)));

constexpr int K1 = 4096;
constexpr int N1 = 512;
constexpr int TT = 64;
constexpr int NC = 40;
constexpr float EPS  = 1e-4f;   // LIF1 flag threshold (~6.3 sigma of fast-path err)
constexpr float EPS2 = 1e-5f;   // LIF2 flag threshold (~20 sigma)
constexpr unsigned CAP  = 8192;
constexpr unsigned CAP2 = 1024;

// ws layout (bytes) — high-water identical to R5-R8 (50.46 MB)
constexpr size_t S_OFF    = 0;            // 16384*512 f32 = 33.5 MB
constexpr size_t W1T_OFF  = 33554432;     // [512][4096] f32 (fixup1)
constexpr size_t PKH_OFF  = 41943040;     // W1 pack hi, 4 MB  (aliased by yfix after gemm)
constexpr size_t PKM_OFF  = 46137344;     // W1 pack mid, 4 MB (aliased by w2pk/ssum/list2 after gemm)
constexpr size_t CNT_OFF  = 50331648;     // cnt (u32) + cnt2 (u32)
constexpr size_t LIST_OFF = 50331904;     // CAP u32
// aliases (used only after gemm_fast has consumed pkh/pkm):
constexpr size_t YFIX_OFF  = PKH_OFF;                 // CAP * 64 f64 = 4 MB
constexpr size_t W2PK_OFF  = PKM_OFF;                 // 3 * 64KB packs
constexpr size_t SSUM_OFF  = PKM_OFF + 196608;        // 256*40 f32
constexpr size_t LIST2_OFF = PKM_OFF + 237568;        // CAP2 u32

union U8 { ushort u[8]; uint4 v; };
union BC { __bf16 b; ushort s; };

__device__ __forceinline__ void split_pair(float f0, float f1,
                                           unsigned& hp, unsigned& mp) {
  asm("v_cvt_pk_bf16_f32 %0, %1, %2" : "=v"(hp) : "v"(f0), "v"(f1));
  unsigned h0b = hp << 16;
  unsigned h1b = hp & 0xFFFF0000u;
  float m0 = f0 - __builtin_bit_cast(float, h0b);
  float m1 = f1 - __builtin_bit_cast(float, h1b);
  asm("v_cvt_pk_bf16_f32 %0, %1, %2" : "=v"(mp) : "v"(m0), "v"(m1));
}

// ---------------------------------------------------------------------------
// prep: W1 -> W1T (f32 [n][k]) + MFMA B-frag-ordered bf16 hi/mid packs.
// ---------------------------------------------------------------------------
__global__ __launch_bounds__(256) void prep(const float* __restrict__ W1,
                                            float* __restrict__ W1T,
                                            uint4* __restrict__ pkh,
                                            uint4* __restrict__ pkm) {
  __shared__ float tile[64][65];
  const int tid = threadIdx.x;
  const int kb = blockIdx.x * 64;
  const int nb = blockIdx.y * 64;
  const int r  = tid >> 2;
  const int c0 = (tid & 3) * 16;
  const float4* src = (const float4*)(W1 + (size_t)(kb + r) * N1 + nb + c0);
#pragma unroll
  for (int u = 0; u < 4; ++u) {
    float4 v = src[u];
    tile[r][c0 + u * 4 + 0] = v.x;
    tile[r][c0 + u * 4 + 1] = v.y;
    tile[r][c0 + u * 4 + 2] = v.z;
    tile[r][c0 + u * 4 + 3] = v.w;
  }
  __syncthreads();
  const size_t ob = (size_t)(nb + r) * K1 + kb + c0;
#pragma unroll
  for (int u = 0; u < 4; ++u) {
    float4 o = make_float4(tile[c0 + u * 4 + 0][r], tile[c0 + u * 4 + 1][r],
                           tile[c0 + u * 4 + 2][r], tile[c0 + u * 4 + 3][r]);
    *(float4*)(W1T + ob + u * 4) = o;
  }
#pragma unroll
  for (int sl = 0; sl < 2; ++sl) {
    const int slot = tid + sl * 256;
    const int frag_loc = slot >> 6, lane = slot & 63;
    const int kc_loc = frag_loc >> 1, s_loc = frag_loc & 1;
    const int n_loc = s_loc * 32 + (lane & 31);
    const int k_base = kc_loc * 16 + (lane >> 5) * 8;
    uint4 hh, mm;
    unsigned* hw = (unsigned*)&hh;
    unsigned* mw = (unsigned*)&mm;
#pragma unroll
    for (int p = 0; p < 4; ++p)
      split_pair(tile[k_base + 2 * p][n_loc], tile[k_base + 2 * p + 1][n_loc],
                 hw[p], mw[p]);
    const size_t f = (size_t)((nb >> 5) + s_loc) * 256 + (kb >> 4) + kc_loc;
    pkh[f * 64 + lane] = hh;
    pkm[f * 64 + lane] = mm;
  }
}

// ---------------------------------------------------------------------------
// gemm_fast: unchanged R8 structure (3-term split, dbuf A LDS, B reg pingpong).
// ---------------------------------------------------------------------------
__global__ __launch_bounds__(256, 2) void gemm_fast(const float* __restrict__ x,
                                                    const uint4* __restrict__ pkh,
                                                    const uint4* __restrict__ pkm,
                                                    const float* __restrict__ b1,
                                                    float* __restrict__ S,
                                                    unsigned* __restrict__ cnt,
                                                    unsigned* __restrict__ list) {
  __shared__ __attribute__((aligned(16))) char lds[32768];
  float* const dS = (float*)lds;

  const int tid = threadIdx.x;
  const int lane = tid & 63, wid = tid >> 6;
  const int lr = lane & 31;
  const int wm = (wid & 1) * 64;
  const int wq = wid >> 1;

  const int id = blockIdx.x;
  const int xcd = id & 7, sq = id >> 3;
  const int m_blk = xcd * 16 + (sq >> 2);
  const int n_blk = sq & 3;
  const int bm = m_blk * 128, bn = n_blk * 128;

  const int ar = tid >> 1, akh = tid & 1;
  const float* Ap = x + (size_t)(bm + ar) * K1 + akh * 16;
  const int wr0 = (akh * 4 + (ar >> 5)) * 1024 + (ar & 31) * 16;

  const int s0 = n_blk * 4 + wq * 2;
  const uint4* pbh[2][2];
  const uint4* pbm[2][2];
#pragma unroll
  for (int kh = 0; kh < 2; ++kh)
#pragma unroll
    for (int nt = 0; nt < 2; ++nt) {
      const size_t base = ((size_t)(s0 + nt) * 256 + kh) * 64 + lane;
      pbh[kh][nt] = pkh + base;
      pbm[kh][nt] = pkm + base;
    }

  f32x16 acc[2][2] = {};
  float4 av[4];
  uint4 bch[2][2], bcm[2][2], bnh[2][2], bnm[2][2];

#pragma unroll
  for (int u = 0; u < 4; ++u) av[u] = *(const float4*)(Ap + u * 4);
#pragma unroll
  for (int kh = 0; kh < 2; ++kh)
#pragma unroll
    for (int nt = 0; nt < 2; ++nt) {
      bch[kh][nt] = pbh[kh][nt][0];
      bcm[kh][nt] = pbm[kh][nt][0];
      bnh[kh][nt] = pbh[kh][nt][32 * 4];
      bnm[kh][nt] = pbm[kh][nt][32 * 4];
    }

  {
    uint4 hi[2], mi[2];
    unsigned* hw = (unsigned*)hi;
    unsigned* mw = (unsigned*)mi;
#pragma unroll
    for (int u = 0; u < 4; ++u) {
      split_pair(av[u].x, av[u].y, hw[2 * u], mw[2 * u]);
      split_pair(av[u].z, av[u].w, hw[2 * u + 1], mw[2 * u + 1]);
    }
    *(uint4*)(lds + wr0)              = hi[0];
    *(uint4*)(lds + wr0 + 512)        = hi[1];
    *(uint4*)(lds + 8192 + wr0)       = mi[0];
    *(uint4*)(lds + 8192 + wr0 + 512) = mi[1];
#pragma unroll
    for (int u = 0; u < 4; ++u) av[u] = *(const float4*)(Ap + 32 + u * 4);
  }

  for (int k0 = 0; k0 < K1; k0 += 32) {
    const int cur = (k0 >> 5) & 1;
    char* const bufc = lds + cur * 16384;
    char* const bufn = lds + (cur ^ 1) * 16384;
    __syncthreads();

    if (k0 + 32 < K1) {
      uint4 hi[2], mi[2];
      unsigned* hw = (unsigned*)hi;
      unsigned* mw = (unsigned*)mi;
#pragma unroll
      for (int u = 0; u < 4; ++u) {
        split_pair(av[u].x, av[u].y, hw[2 * u], mw[2 * u]);
        split_pair(av[u].z, av[u].w, hw[2 * u + 1], mw[2 * u + 1]);
      }
      *(uint4*)(bufn + wr0)              = hi[0];
      *(uint4*)(bufn + wr0 + 512)        = hi[1];
      *(uint4*)(bufn + 8192 + wr0)       = mi[0];
      *(uint4*)(bufn + 8192 + wr0 + 512) = mi[1];
    }
    if (k0 + 64 < K1) {
#pragma unroll
      for (int u = 0; u < 4; ++u) av[u] = *(const float4*)(Ap + k0 + 64 + u * 4);
    }

#pragma unroll
    for (int kh = 0; kh < 2; ++kh) {
#pragma unroll
      for (int mt = 0; mt < 2; ++mt) {
        const int region = (kh * 4 + (wm >> 5) + mt) * 1024 + lane * 16;
        bf16x8 ah = *(const bf16x8*)(bufc + region);
        bf16x8 am = *(const bf16x8*)(bufc + 8192 + region);
#pragma unroll
        for (int nt = 0; nt < 2; ++nt) {
          const bf16x8 vbh = __builtin_bit_cast(bf16x8, bch[kh][nt]);
          const bf16x8 vbm = __builtin_bit_cast(bf16x8, bcm[kh][nt]);
          acc[mt][nt] = __builtin_amdgcn_mfma_f32_32x32x16_bf16(am, vbh, acc[mt][nt], 0, 0, 0);
          acc[mt][nt] = __builtin_amdgcn_mfma_f32_32x32x16_bf16(ah, vbm, acc[mt][nt], 0, 0, 0);
          acc[mt][nt] = __builtin_amdgcn_mfma_f32_32x32x16_bf16(ah, vbh, acc[mt][nt], 0, 0, 0);
        }
      }
    }

#pragma unroll
    for (int kh = 0; kh < 2; ++kh)
#pragma unroll
      for (int nt = 0; nt < 2; ++nt) {
        bch[kh][nt] = bnh[kh][nt];
        bcm[kh][nt] = bnm[kh][nt];
      }
    if (k0 + 64 < K1) {
      const int off = (k0 + 64) * 4;
#pragma unroll
      for (int kh = 0; kh < 2; ++kh)
#pragma unroll
        for (int nt = 0; nt < 2; ++nt) {
          bnh[kh][nt] = pbh[kh][nt][off];
          bnm[kh][nt] = pbm[kh][nt][off];
        }
    }
  }

#pragma unroll
  for (int half = 0; half < 2; ++half) {
    __syncthreads();
    if ((wid & 1) == half) {
      const int lhi = lane >> 5;
#pragma unroll
      for (int mt = 0; mt < 2; ++mt)
#pragma unroll
        for (int nt = 0; nt < 2; ++nt)
#pragma unroll
          for (int r = 0; r < 16; ++r) {
            const int row = mt * 32 + (r & 3) + 8 * (r >> 2) + 4 * lhi;
            const int col = wq * 64 + nt * 32 + lr;
            dS[row * 128 + col] = acc[mt][nt][r];
          }
    }
    __syncthreads();
    if (tid < 128) {
      const int n = tid;
      const int b = m_blk * 2 + half;
      const float bias = b1[bn + n];
      float mem = 0.0f, spk = 0.0f, mn = 1e9f;
      for (int t = 0; t < TT; ++t) {
        const float y = dS[t * 128 + n] + bias;
        mem = mem * 0.5f * (1.0f - spk) + y;
        const float d = mem - 1.0f;
        mn = fminf(mn, fabsf(d));
        spk = (d > 0.0f) ? 1.0f : 0.0f;
        S[((size_t)(b * TT + t)) * N1 + bn + n] = spk;
      }
      if (mn < EPS) {
        unsigned idx = atomicAdd(cnt, 1u);
        if (idx < CAP) list[idx] = ((unsigned)b << 16) | (unsigned)(bn + n);
      }
    }
  }
}

// ---------------------------------------------------------------------------
// fixup_dots: work item = (entry, quarter); block computes 16 fp64 dot rows
// (coalesced 1KB wave-loads) -> yfix[e][t]. Grid 2048 -> full HBM BW.
// ---------------------------------------------------------------------------
__global__ __launch_bounds__(256) void fixup_dots(const float* __restrict__ x,
                                                  const float* __restrict__ W1T,
                                                  const unsigned* __restrict__ cnt,
                                                  const unsigned* __restrict__ list,
                                                  double* __restrict__ yfix) {
  const int tid = threadIdx.x;
  const int lane = tid & 63, w = tid >> 6;
  const int count = (int)min(*cnt, CAP);

  for (int item = blockIdx.x; item < count * 4; item += gridDim.x) {
    const int e = item >> 2, quarter = item & 3;
    const unsigned ent = list[e];
    const int b = (int)(ent >> 16), n = (int)(ent & 0xffffu);
    const float4* wr = (const float4*)(W1T + (size_t)n * K1);
#pragma unroll
    for (int i = 0; i < 4; ++i) {
      const int t = quarter * 16 + w * 4 + i;
      const float4* xr = (const float4*)(x + ((size_t)(b * TT + t)) * K1);
      double p = 0.0;
#pragma unroll
      for (int j = 0; j < 16; ++j) {
        const float4 xv = xr[lane + 64 * j];
        const float4 wv = wr[lane + 64 * j];
        p += (double)xv.x * (double)wv.x + (double)xv.y * (double)wv.y +
             (double)xv.z * (double)wv.z + (double)xv.w * (double)wv.w;
      }
#pragma unroll
      for (int off = 1; off < 64; off <<= 1) p += __shfl_xor(p, off);
      if (lane == 0) yfix[(size_t)e * TT + t] = p;
    }
  }
}

// ---------------------------------------------------------------------------
// fixup_apply: one thread per entry; fp64 LIF replay from yfix, overwrite S.
// ---------------------------------------------------------------------------
__global__ __launch_bounds__(256) void fixup_apply(const double* __restrict__ yfix,
                                                   const float* __restrict__ b1,
                                                   const unsigned* __restrict__ cnt,
                                                   const unsigned* __restrict__ list,
                                                   float* __restrict__ S) {
  const int count = (int)min(*cnt, CAP);
  for (int e = blockIdx.x * 256 + threadIdx.x; e < count; e += gridDim.x * 256) {
    const unsigned ent = list[e];
    const int b = (int)(ent >> 16), n = (int)(ent & 0xffffu);
    double mem = 0.0, spk = 0.0;
    const double bias = (double)b1[n];
    for (int t = 0; t < TT; ++t) {
      const double y = yfix[(size_t)e * TT + t] + bias;
      mem = mem * 0.5 * (1.0 - spk) + y;
      spk = (mem > 1.0) ? 1.0 : 0.0;
      S[((size_t)(b * TT + t)) * N1 + n] = (float)spk;
    }
  }
}

// ---------------------------------------------------------------------------
// prep_w2: W2 [512][40] f32 -> 3 exact bf16 splits (hi+mid+lo == w), frag
// order for 32x32x16, N padded to 64 with zeros. 64 blocks x 64 threads.
// ---------------------------------------------------------------------------
__global__ __launch_bounds__(64) void prep_w2(const float* __restrict__ W2,
                                              uint4* __restrict__ p2h,
                                              uint4* __restrict__ p2m,
                                              uint4* __restrict__ p2l) {
  const int f = blockIdx.x;            // f = s*32 + kc
  const int lane = threadIdx.x;
  const int s = f >> 5, kc = f & 31;
  const int n = s * 32 + (lane & 31);
  const int kb = kc * 16 + (lane >> 5) * 8;
  U8 hh, mm, ll;
#pragma unroll
  for (int j = 0; j < 8; ++j) {
    const float w = (n < NC) ? W2[(size_t)(kb + j) * NC + n] : 0.0f;
    __bf16 h = (__bf16)w;  float r1 = w - (float)h;
    __bf16 m = (__bf16)r1; float r2 = r1 - (float)m;
    __bf16 l = (__bf16)r2;
    BC ch; ch.b = h; BC cm; cm.b = m; BC cl; cl.b = l;
    hh.u[j] = ch.s; mm.u[j] = cm.s; ll.u[j] = cl.s;
  }
  p2h[(size_t)f * 64 + lane] = hh.v;
  p2m[(size_t)f * 64 + lane] = mm.v;
  p2l[(size_t)f * 64 + lane] = ll.v;
}

// ---------------------------------------------------------------------------
// head_mfma: per batch b: Y = S[b] (64x512, exact bf16) @ W2 (3 exact splits)
// via 32x32x16 MFMA, f32 accum; fused f32 LIF2 + margin flagging; writes
// per-(b,c) spike counts to ssum. 256 blocks x 256 thr (4 waves, 2m x 2n).
// ---------------------------------------------------------------------------
__global__ __launch_bounds__(256) void head_mfma(const float* __restrict__ S,
                                                 const uint4* __restrict__ p2h,
                                                 const uint4* __restrict__ p2m,
                                                 const uint4* __restrict__ p2l,
                                                 const float* __restrict__ b2,
                                                 float* __restrict__ ssum,
                                                 unsigned* __restrict__ cnt2,
                                                 unsigned* __restrict__ list2) {
  __shared__ __attribute__((aligned(16))) char lds[16384];
  float* const dS = (float*)lds;       // [64 t][64 n] f32 epilogue alias
  char* const buf = lds;               // [64 r][128 B] bf16 staging (8 KB)

  const int tid = threadIdx.x;
  const int lane = tid & 63, wid = tid >> 6;
  const int wm2 = wid & 1, wn2 = wid >> 1;
  const int b = blockIdx.x;

  // staging map: row = tid>>2 (t), 16 f32 per thread
  const int srow_ = tid >> 2, scol = (tid & 3) * 16;
  const float* Sp = S + ((size_t)(b * TT + srow_)) * N1 + scol;
  const int wb0 = srow_ * 128 + scol * 2;
  const int swz = (srow_ & 7) << 4;

  // A-frag read offset (swizzle consistent with writes)
  const int trow = wm2 * 32 + (lane & 31);
  const int aswz = (trow & 7) << 4;

  f32x16 acc = {};

  for (int step = 0; step < 8; ++step) {
    // load + exact bf16 convert
    float4 v[4];
#pragma unroll
    for (int u = 0; u < 4; ++u) v[u] = *(const float4*)(Sp + step * 64 + u * 4);
    uint4 o0, o1;
    unsigned* ow = (unsigned*)&o0;   // o0,o1 contiguous? use array
    unsigned owv[8];
#pragma unroll
    for (int u = 0; u < 4; ++u) {
      unsigned dummy_m0, dummy_m1;
      split_pair(v[u].x, v[u].y, owv[2 * u], dummy_m0);
      split_pair(v[u].z, v[u].w, owv[2 * u + 1], dummy_m1);
      (void)dummy_m0; (void)dummy_m1;
    }
    o0 = make_uint4(owv[0], owv[1], owv[2], owv[3]);
    o1 = make_uint4(owv[4], owv[5], owv[6], owv[7]);
    (void)ow;
    __syncthreads();   // prior MFMA reads done
    *(uint4*)(buf + ((wb0)      ^ swz)) = o0;
    *(uint4*)(buf + ((wb0 + 16) ^ swz)) = o1;
    __syncthreads();   // writes visible

#pragma unroll
    for (int kcl = 0; kcl < 4; ++kcl) {
      const int abyte = (trow * 128 + kcl * 32 + (lane >> 5) * 16) ^ aswz;
      const bf16x8 af = *(const bf16x8*)(buf + abyte);
      const size_t fidx = ((size_t)wn2 * 32 + step * 4 + kcl) * 64 + lane;
      const bf16x8 bh = __builtin_bit_cast(bf16x8, p2h[fidx]);
      const bf16x8 bm = __builtin_bit_cast(bf16x8, p2m[fidx]);
      const bf16x8 bl = __builtin_bit_cast(bf16x8, p2l[fidx]);
      acc = __builtin_amdgcn_mfma_f32_32x32x16_bf16(af, bl, acc, 0, 0, 0);
      acc = __builtin_amdgcn_mfma_f32_32x32x16_bf16(af, bm, acc, 0, 0, 0);
      acc = __builtin_amdgcn_mfma_f32_32x32x16_bf16(af, bh, acc, 0, 0, 0);
    }
  }

  __syncthreads();
#pragma unroll
  for (int r = 0; r < 16; ++r) {
    const int row = wm2 * 32 + (r & 3) + 8 * (r >> 2) + 4 * (lane >> 5);
    const int col = wn2 * 32 + (lane & 31);
    dS[row * 64 + col] = acc[r];
  }
  __syncthreads();

  if (tid < NC) {
    const float bias = b2[tid];
    float mem = 0.0f, spk = 0.0f, mn = 1e9f, ss = 0.0f;
    for (int t = 0; t < TT; ++t) {
      const float y = dS[t * 64 + tid] + bias;
      mem = mem * 0.5f * (1.0f - spk) + y;
      const float d = mem - 1.0f;
      mn = fminf(mn, fabsf(d));
      spk = (d > 0.0f) ? 1.0f : 0.0f;
      ss += spk;
    }
    ssum[b * NC + tid] = ss;
    if (mn < EPS2) {
      unsigned idx = atomicAdd(cnt2, 1u);
      if (idx < CAP2) list2[idx] = ((unsigned)b << 8) | (unsigned)tid;
    }
  }
}

// ---------------------------------------------------------------------------
// fixup2: per flagged (b,c): fp64 GEMM2 column + LIF2 replay, patch ssum.
// ---------------------------------------------------------------------------
__global__ __launch_bounds__(256) void fixup2(const float* __restrict__ S,
                                              const float* __restrict__ W2,
                                              const float* __restrict__ b2,
                                              const unsigned* __restrict__ cnt2,
                                              const unsigned* __restrict__ list2,
                                              float* __restrict__ ssum) {
  __shared__ float w2c[N1];
  __shared__ double y2[TT];
  const int tid = threadIdx.x;
  const int count = (int)min(*cnt2, CAP2);

  for (int e = blockIdx.x; e < count; e += gridDim.x) {
    const unsigned ent = list2[e];
    const int b = (int)(ent >> 8), c = (int)(ent & 255u);
    for (int h = tid; h < N1; h += 256) w2c[h] = W2[(size_t)h * NC + c];
    __syncthreads();
    const int t = tid >> 2, q = tid & 3;
    const float* sr = S + ((size_t)(b * TT + t)) * N1 + q * 128;
    double p = 0.0;
    for (int j = 0; j < 128; ++j) p += (double)sr[j] * (double)w2c[q * 128 + j];
    p += __shfl_xor(p, 1);
    p += __shfl_xor(p, 2);
    if (q == 0) y2[t] = p;
    __syncthreads();
    if (tid == 0) {
      double mem = 0.0, spk = 0.0, ss = 0.0;
      const double bias = (double)b2[c];
      for (int t2 = 0; t2 < TT; ++t2) {
        const double y = y2[t2] + bias;
        mem = mem * 0.5 * (1.0 - spk) + y;
        spk = (mem > 1.0) ? 1.0 : 0.0;
        ss += spk;
      }
      ssum[b * NC + c] = (float)ss;
    }
    __syncthreads();
  }
}

// ---------------------------------------------------------------------------
// pool: out[b][g] = sum_{j<10} ssum[b][g*10+j] / 640 (fp64).
// ---------------------------------------------------------------------------
__global__ __launch_bounds__(256) void pool(const float* __restrict__ ssum,
                                            float* __restrict__ out) {
  const int i = blockIdx.x * 256 + threadIdx.x;
  if (i < 1024) {
    const int b = i >> 2, g = i & 3;
    double s = 0.0;
#pragma unroll
    for (int j = 0; j < 10; ++j) s += (double)ssum[b * NC + g * 10 + j];
    out[i] = (float)(s * (1.0 / 640.0));
  }
}

extern "C" void kernel_launch(void* const* d_in, const int* in_sizes, int n_in,
                              void* d_out, int out_size, void* d_ws, size_t ws_size,
                              hipStream_t stream) {
  const float* x  = (const float*)d_in[0];
  const float* W1 = (const float*)d_in[1];
  const float* b1 = (const float*)d_in[2];
  const float* W2 = (const float*)d_in[3];
  const float* b2 = (const float*)d_in[4];
  float* out = (float*)d_out;

  char* ws = (char*)d_ws;
  float*    Sb    = (float*)(ws + S_OFF);
  float*    W1T   = (float*)(ws + W1T_OFF);
  uint4*    pkh   = (uint4*)(ws + PKH_OFF);
  uint4*    pkm   = (uint4*)(ws + PKM_OFF);
  unsigned* cnt   = (unsigned*)(ws + CNT_OFF);      // [0]=cnt1, [1]=cnt2
  unsigned* list  = (unsigned*)(ws + LIST_OFF);
  double*   yfix  = (double*)(ws + YFIX_OFF);       // alias pkh (post-gemm)
  uint4*    p2h   = (uint4*)(ws + W2PK_OFF);        // alias pkm (post-gemm)
  uint4*    p2m   = (uint4*)(ws + W2PK_OFF + 65536);
  uint4*    p2l   = (uint4*)(ws + W2PK_OFF + 131072);
  float*    ssumb = (float*)(ws + SSUM_OFF);
  unsigned* list2 = (unsigned*)(ws + LIST2_OFF);

  hipMemsetAsync(cnt, 0, 8, stream);
  prep<<<dim3(64, 8), dim3(256), 0, stream>>>(W1, W1T, pkh, pkm);
  gemm_fast<<<dim3(512), dim3(256), 0, stream>>>(x, pkh, pkm, b1, Sb, cnt, list);
  fixup_dots<<<dim3(2048), dim3(256), 0, stream>>>(x, W1T, cnt, list, yfix);
  fixup_apply<<<dim3(16), dim3(256), 0, stream>>>(yfix, b1, cnt, list, Sb);
  prep_w2<<<dim3(64), dim3(64), 0, stream>>>(W2, p2h, p2m, p2l);
  head_mfma<<<dim3(256), dim3(256), 0, stream>>>(Sb, p2h, p2m, p2l, b2, ssumb, cnt + 1, list2);
  fixup2<<<dim3(64), dim3(256), 0, stream>>>(Sb, W2, b2, cnt + 1, list2, ssumb);
  pool<<<dim3(4), dim3(256), 0, stream>>>(ssumb, out);
}